// Round 1
// baseline (1183.159 us; speedup 1.0000x reference)
//
#include <hip/hip_runtime.h>
#include <hip/hip_bf16.h>
#include <math.h>

#define D 128
#define G_GRAPHS 512
#define C_CLASSES 10
#define BN_EPS 1e-5f

// ---------------- degree / dinv ----------------
__global__ void deg_count_kernel(const int* __restrict__ dst, int* __restrict__ degi, int E) {
    int i = blockIdx.x * blockDim.x + threadIdx.x;
    if (i < E) atomicAdd(&degi[dst[i]], 1);
}

__global__ void deg_to_dinv_kernel(const int* __restrict__ degi, float* __restrict__ dinv, int n) {
    int i = blockIdx.x * blockDim.x + threadIdx.x;
    if (i < n) dinv[i] = rsqrtf((float)(degi[i] + 1));  // +1 self loop, always >= 1
}

// ---------------- scan (CSR row_ptr) ----------------
// chunked inclusive scan: 256 elems per block
__global__ void scan1_kernel(const int* __restrict__ in, int* __restrict__ incl,
                             int* __restrict__ partials, int n) {
    __shared__ int buf[2][256];
    int tid = threadIdx.x;
    int gid = blockIdx.x * 256 + tid;
    int v = (gid < n) ? in[gid] : 0;
    buf[0][tid] = v;
    __syncthreads();
    int cur = 0;
    for (int off = 1; off < 256; off <<= 1) {
        buf[1 - cur][tid] = buf[cur][tid] + ((tid >= off) ? buf[cur][tid - off] : 0);
        cur ^= 1;
        __syncthreads();
    }
    if (gid < n) incl[gid] = buf[cur][tid];
    if (tid == 255) partials[blockIdx.x] = buf[cur][tid];
}

// single-block exclusive scan in place (nb <= 512)
__global__ void scan2_kernel(int* __restrict__ partials, int nb) {
    __shared__ int buf[2][512];
    int tid = threadIdx.x;
    int v = (tid < nb) ? partials[tid] : 0;
    buf[0][tid] = v;
    __syncthreads();
    int cur = 0;
    for (int off = 1; off < 512; off <<= 1) {
        buf[1 - cur][tid] = buf[cur][tid] + ((tid >= off) ? buf[cur][tid - off] : 0);
        cur ^= 1;
        __syncthreads();
    }
    if (tid < nb) partials[tid] = buf[cur][tid] - v;  // exclusive
}

__global__ void scan3_kernel(const int* __restrict__ incl, const int* __restrict__ base,
                             const int* __restrict__ deg, int* __restrict__ rowPtr,
                             int* __restrict__ cursor, int n, int total) {
    int gid = blockIdx.x * 256 + threadIdx.x;
    if (gid < n) {
        int v = base[gid >> 8] + incl[gid] - deg[gid];  // exclusive
        rowPtr[gid] = v;
        cursor[gid] = v;
    } else if (gid == n) {
        rowPtr[n] = total;
    }
}

__global__ void fill_csr_kernel(const int* __restrict__ src, const int* __restrict__ dst,
                                int* __restrict__ cursor, int* __restrict__ colIdx, int E) {
    int i = blockIdx.x * blockDim.x + threadIdx.x;
    if (i < E) {
        int d = dst[i];
        int pos = atomicAdd(&cursor[d], 1);
        colIdx[pos] = src[i];
    }
}

// ---------------- graph segments ----------------
__global__ void graph_count_kernel(const int* __restrict__ batch, int* __restrict__ gcnt, int n) {
    int i = blockIdx.x * blockDim.x + threadIdx.x;
    if (i < n) atomicAdd(&gcnt[batch[i]], 1);
}

__global__ void scan_graphs_kernel(const int* __restrict__ cnt, int* __restrict__ start) {
    __shared__ int buf[2][512];
    int tid = threadIdx.x;  // exactly 512 threads
    int v = cnt[tid];
    buf[0][tid] = v;
    __syncthreads();
    int cur = 0;
    for (int off = 1; off < 512; off <<= 1) {
        buf[1 - cur][tid] = buf[cur][tid] + ((tid >= off) ? buf[cur][tid - off] : 0);
        cur ^= 1;
        __syncthreads();
    }
    start[tid] = buf[cur][tid] - v;
}

// ---------------- GEMM: Y = act(X) @ W, X:(n,128), W:(128,128) ----------------
// optional fused input transform: x' = relu(x*scale[k] + shift[k])   (bn+relu)
#define GEMM_ROWS 32
__global__ __launch_bounds__(256) void gemm128_kernel(
    const float* __restrict__ X, const float* __restrict__ W,
    const float* __restrict__ scale, const float* __restrict__ shift,
    float* __restrict__ Y, int nrows)
{
    __shared__ float xs[GEMM_ROWS * D];   // 16 KB
    __shared__ float ws[D * D];           // 64 KB
    int tid = threadIdx.x;
    int row0 = blockIdx.x * GEMM_ROWS;
    bool fuse = (scale != nullptr);

#pragma unroll
    for (int i = 0; i < 64; ++i) ws[tid + i * 256] = W[tid + i * 256];

#pragma unroll
    for (int i = 0; i < GEMM_ROWS * D / 256; ++i) {
        int idx = tid + i * 256;
        int r = idx >> 7, k = idx & 127;
        int gr = row0 + r;
        float v = (gr < nrows) ? X[(size_t)gr * D + k] : 0.f;
        if (fuse) v = fmaxf(v * scale[k] + shift[k], 0.f);
        xs[idx] = v;
    }
    __syncthreads();

    int cg = tid & 31;          // cols cg, cg+32, cg+64, cg+96 (lane-striped: conflict-free)
    int rg = (tid >> 5) * 4;    // rows rg..rg+3
    float acc[4][4] = {};
#pragma unroll 4
    for (int k = 0; k < D; ++k) {
        float w0 = ws[k * D + cg];
        float w1 = ws[k * D + cg + 32];
        float w2 = ws[k * D + cg + 64];
        float w3 = ws[k * D + cg + 96];
#pragma unroll
        for (int j = 0; j < 4; ++j) {
            float xv = xs[(rg + j) * D + k];
            acc[j][0] += xv * w0;
            acc[j][1] += xv * w1;
            acc[j][2] += xv * w2;
            acc[j][3] += xv * w3;
        }
    }
#pragma unroll
    for (int j = 0; j < 4; ++j) {
        int gr = row0 + rg + j;
        if (gr < nrows) {
            float* yp = &Y[(size_t)gr * D];
            yp[cg] = acc[j][0];
            yp[cg + 32] = acc[j][1];
            yp[cg + 64] = acc[j][2];
            yp[cg + 96] = acc[j][3];
        }
    }
}

// ---------------- aggregation: out = relu(dinv[v]*(sum_u dinv[u]*T[u] + dinv[v]*T[v]) + b) ----
// one wave per row; CSR, no atomics
__global__ __launch_bounds__(256) void aggregate_kernel(
    const float* __restrict__ T, const int* __restrict__ colIdx,
    const int* __restrict__ rowPtr, const float* __restrict__ dinv,
    const float* __restrict__ bias, float* __restrict__ outH, int n)
{
    int wid = threadIdx.x >> 6;
    int lane = threadIdx.x & 63;
    int row = blockIdx.x * 4 + wid;
    if (row >= n) return;

    float dr = dinv[row];
    const float2* Ts = (const float2*)T;
    float2 tv = Ts[(size_t)row * 64 + lane];
    float ax = dr * tv.x, ay = dr * tv.y;  // self loop (gets another *dr below)

    int s = rowPtr[row], e = rowPtr[row + 1];
    for (int j0 = s; j0 < e; j0 += 64) {
        int m = e - j0;
        if (m > 64) m = 64;
        int u = 0;
        float du = 0.f;
        if (lane < m) {
            u = colIdx[j0 + lane];
            du = dinv[u];
        }
        for (int t = 0; t < m; ++t) {
            int uu = __shfl(u, t);
            float duu = __shfl(du, t);
            float2 tw = Ts[(size_t)uu * 64 + lane];
            ax += duu * tw.x;
            ay += duu * tw.y;
        }
    }
    const float2* bp = (const float2*)bias;
    float2 b = bp[lane];
    float2 o;
    o.x = fmaxf(dr * ax + b.x, 0.f);
    o.y = fmaxf(dr * ay + b.y, 0.f);
    ((float2*)outH)[(size_t)row * 64 + lane] = o;
}

// ---------------- batchnorm stats ----------------
__global__ __launch_bounds__(256) void bn_stats_kernel(
    const float* __restrict__ H, int n, float* __restrict__ gsum, float* __restrict__ gsq)
{
    int tid = threadIdx.x;
    int col = tid & 127;
    float s = 0.f, s2 = 0.f;
    for (int row = blockIdx.x * 2 + (tid >> 7); row < n; row += gridDim.x * 2) {
        float v = H[(size_t)row * D + col];
        s += v;
        s2 += v * v;
    }
    __shared__ float sh[256], sh2[256];
    sh[tid] = s;
    sh2[tid] = s2;
    __syncthreads();
    if (tid < 128) {
        atomicAdd(&gsum[col], sh[tid] + sh[tid + 128]);
        atomicAdd(&gsq[col], sh2[tid] + sh2[tid + 128]);
    }
}

__global__ void bn_finalize_kernel(const float* __restrict__ gsum, const float* __restrict__ gsq,
                                   const float* __restrict__ gamma, const float* __restrict__ beta,
                                   float n, float* __restrict__ scale, float* __restrict__ shift)
{
    int c = threadIdx.x;  // 128
    float mu = gsum[c] / n;
    float var = gsq[c] / n - mu * mu;
    float sc = gamma[c] * rsqrtf(var + BN_EPS);
    scale[c] = sc;
    shift[c] = beta[c] - mu * sc;
}

// ---------------- pooling (fused bn2+relu) ----------------
__global__ __launch_bounds__(128) void pool_kernel(
    const float* __restrict__ H, const float* __restrict__ scale, const float* __restrict__ shift,
    const int* __restrict__ gstart, const int* __restrict__ gcnt, float* __restrict__ pooled)
{
    int g = blockIdx.x;
    int tid = threadIdx.x;  // 128
    int s = gstart[g], c = gcnt[g];
    float sc = scale[tid], sh = shift[tid];
    float a = 0.f;
    for (int i = 0; i < c; ++i) {
        float v = H[(size_t)(s + i) * D + tid];
        a += fmaxf(v * sc + sh, 0.f);
    }
    int cm = c > 1 ? c : 1;
    pooled[(size_t)g * D + tid] = a / (float)cm;
}

// ---------------- classifier + log_softmax ----------------
__global__ __launch_bounds__(64) void classify_kernel(
    const float* __restrict__ pooled, const float* __restrict__ fcw,
    const float* __restrict__ fcb, float* __restrict__ out)
{
    int g = blockIdx.x;
    int tid = threadIdx.x;  // 64
    __shared__ float prow[D];
    __shared__ float lg[C_CLASSES];
    prow[tid] = pooled[(size_t)g * D + tid];
    prow[tid + 64] = pooled[(size_t)g * D + 64 + tid];
    __syncthreads();
    if (tid < C_CLASSES) {
        float s = fcb[tid];
        for (int d = 0; d < D; ++d) s += prow[d] * fcw[d * C_CLASSES + tid];
        lg[tid] = s;
    }
    __syncthreads();
    if (tid == 0) {
        float m = -1e30f;
        for (int c = 0; c < C_CLASSES; ++c) m = fmaxf(m, lg[c]);
        float se = 0.f;
        for (int c = 0; c < C_CLASSES; ++c) se += expf(lg[c] - m);
        float lse = m + logf(se);
        for (int c = 0; c < C_CLASSES; ++c) out[(size_t)g * C_CLASSES + c] = lg[c] - lse;
    }
}

extern "C" void kernel_launch(void* const* d_in, const int* in_sizes, int n_in,
                              void* d_out, int out_size, void* d_ws, size_t ws_size,
                              hipStream_t stream) {
    const float* x   = (const float*)d_in[0];
    const int* ei    = (const int*)d_in[1];
    const int* batch = (const int*)d_in[2];
    const float* w1  = (const float*)d_in[3];
    const float* b1  = (const float*)d_in[4];
    const float* w2  = (const float*)d_in[5];
    const float* b2  = (const float*)d_in[6];
    const float* w3  = (const float*)d_in[7];
    const float* b3  = (const float*)d_in[8];
    const float* g1  = (const float*)d_in[9];
    const float* be1 = (const float*)d_in[10];
    const float* g2  = (const float*)d_in[11];
    const float* be2 = (const float*)d_in[12];
    const float* fcw = (const float*)d_in[13];
    const float* fcb = (const float*)d_in[14];

    const int N = in_sizes[0] / D;
    const int E = in_sizes[1] / 2;
    const int* src = ei;
    const int* dst = ei + E;

    // workspace carve (256B aligned)
    char* p = (char*)d_ws;
    auto alloc = [&](size_t bytes) -> void* {
        void* r = (void*)p;
        p += (bytes + 255) & ~(size_t)255;
        return r;
    };
    int*   degi    = (int*)alloc((size_t)N * 4);
    float* dinv    = (float*)alloc((size_t)N * 4);
    int*   rowPtr  = (int*)alloc((size_t)(N + 1) * 4);
    int*   cursor  = (int*)alloc((size_t)N * 4);
    int*   incl    = (int*)alloc((size_t)N * 4);
    int*   partials= (int*)alloc(512 * 4);
    int*   colIdx  = (int*)alloc((size_t)E * 4);
    int*   gcnt    = (int*)alloc(G_GRAPHS * 4);
    int*   gstart  = (int*)alloc(G_GRAPHS * 4);
    float* statsacc= (float*)alloc(4 * D * 4);   // gsum1, gsq1, gsum2, gsq2
    float* gsum1 = statsacc, *gsq1 = statsacc + D, *gsum2 = statsacc + 2 * D, *gsq2 = statsacc + 3 * D;
    float* sc1     = (float*)alloc(D * 4);
    float* sh1     = (float*)alloc(D * 4);
    float* sc2     = (float*)alloc(D * 4);
    float* sh2     = (float*)alloc(D * 4);
    float* pooled  = (float*)alloc((size_t)G_GRAPHS * D * 4);
    float* tmp     = (float*)alloc((size_t)N * D * 4);
    float* hbuf    = (float*)alloc((size_t)N * D * 4);

    hipMemsetAsync(degi, 0, (size_t)N * 4, stream);
    hipMemsetAsync(gcnt, 0, G_GRAPHS * 4, stream);
    hipMemsetAsync(statsacc, 0, 4 * D * 4, stream);

    const int NB = (N + 255) / 256;  // scan chunks

    // graph structure
    deg_count_kernel<<<(E + 255) / 256, 256, 0, stream>>>(dst, degi, E);
    deg_to_dinv_kernel<<<NB, 256, 0, stream>>>(degi, dinv, N);
    scan1_kernel<<<NB, 256, 0, stream>>>(degi, incl, partials, N);
    scan2_kernel<<<1, 512, 0, stream>>>(partials, NB);
    scan3_kernel<<<NB, 256, 0, stream>>>(incl, partials, degi, rowPtr, cursor, N, E);
    fill_csr_kernel<<<(E + 255) / 256, 256, 0, stream>>>(src, dst, cursor, colIdx, E);
    graph_count_kernel<<<NB, 256, 0, stream>>>(batch, gcnt, N);
    scan_graphs_kernel<<<1, 512, 0, stream>>>(gcnt, gstart);

    const int GB = (N + GEMM_ROWS - 1) / GEMM_ROWS;
    const int AB = (N + 3) / 4;

    // layer 1: h = relu(agg(x@w1) + b1)
    gemm128_kernel<<<GB, 256, 0, stream>>>(x, w1, nullptr, nullptr, tmp, N);
    aggregate_kernel<<<AB, 256, 0, stream>>>(tmp, colIdx, rowPtr, dinv, b1, hbuf, N);
    // layer 2
    gemm128_kernel<<<GB, 256, 0, stream>>>(hbuf, w2, nullptr, nullptr, tmp, N);
    aggregate_kernel<<<AB, 256, 0, stream>>>(tmp, colIdx, rowPtr, dinv, b2, hbuf, N);
    // bn1 stats on h2
    bn_stats_kernel<<<512, 256, 0, stream>>>(hbuf, N, gsum1, gsq1);
    bn_finalize_kernel<<<1, 128, 0, stream>>>(gsum1, gsq1, g1, be1, (float)N, sc1, sh1);
    // layer 3 (bn1+relu fused into gemm input)
    gemm128_kernel<<<GB, 256, 0, stream>>>(hbuf, w3, sc1, sh1, tmp, N);
    aggregate_kernel<<<AB, 256, 0, stream>>>(tmp, colIdx, rowPtr, dinv, b3, hbuf, N);
    // bn2 stats on h3
    bn_stats_kernel<<<512, 256, 0, stream>>>(hbuf, N, gsum2, gsq2);
    bn_finalize_kernel<<<1, 128, 0, stream>>>(gsum2, gsq2, g2, be2, (float)N, sc2, sh2);
    // pool (bn2+relu fused) + classify
    pool_kernel<<<G_GRAPHS, 128, 0, stream>>>(hbuf, sc2, sh2, gstart, gcnt, pooled);
    classify_kernel<<<G_GRAPHS, 64, 0, stream>>>(pooled, fcw, fcb, (float*)d_out);
}

// Round 2
// 1105.918 us; speedup vs baseline: 1.0698x; 1.0698x over previous
//
#include <hip/hip_runtime.h>
#include <hip/hip_bf16.h>
#include <math.h>

#define D 128
#define G_GRAPHS 512
#define C_CLASSES 10
#define BN_EPS 1e-5f

__device__ __forceinline__ float bf_lo(unsigned int v) { return __uint_as_float(v << 16); }
__device__ __forceinline__ float bf_hi(unsigned int v) { return __uint_as_float(v & 0xffff0000u); }
__device__ __forceinline__ unsigned short f2bf(float f) {
    union { float f; unsigned int u; } x; x.f = f;
    unsigned int r = x.u + 0x7fff + ((x.u >> 16) & 1);  // RN-even
    return (unsigned short)(r >> 16);
}

// ---------------- degree / dinv ----------------
__global__ void deg_count_kernel(const int* __restrict__ dst, int* __restrict__ degi, int E) {
    int i = blockIdx.x * blockDim.x + threadIdx.x;
    if (i < E) atomicAdd(&degi[dst[i]], 1);
}

__global__ void deg_to_dinv_kernel(const int* __restrict__ degi, float* __restrict__ dinv, int n) {
    int i = blockIdx.x * blockDim.x + threadIdx.x;
    if (i < n) dinv[i] = rsqrtf((float)(degi[i] + 1));  // +1 self loop, always >= 1
}

// ---------------- scan (CSR row_ptr) ----------------
__global__ void scan1_kernel(const int* __restrict__ in, int* __restrict__ incl,
                             int* __restrict__ partials, int n) {
    __shared__ int buf[2][256];
    int tid = threadIdx.x;
    int gid = blockIdx.x * 256 + tid;
    int v = (gid < n) ? in[gid] : 0;
    buf[0][tid] = v;
    __syncthreads();
    int cur = 0;
    for (int off = 1; off < 256; off <<= 1) {
        buf[1 - cur][tid] = buf[cur][tid] + ((tid >= off) ? buf[cur][tid - off] : 0);
        cur ^= 1;
        __syncthreads();
    }
    if (gid < n) incl[gid] = buf[cur][tid];
    if (tid == 255) partials[blockIdx.x] = buf[cur][tid];
}

__global__ void scan2_kernel(int* __restrict__ partials, int nb) {
    __shared__ int buf[2][512];
    int tid = threadIdx.x;
    int v = (tid < nb) ? partials[tid] : 0;
    buf[0][tid] = v;
    __syncthreads();
    int cur = 0;
    for (int off = 1; off < 512; off <<= 1) {
        buf[1 - cur][tid] = buf[cur][tid] + ((tid >= off) ? buf[cur][tid - off] : 0);
        cur ^= 1;
        __syncthreads();
    }
    if (tid < nb) partials[tid] = buf[cur][tid] - v;  // exclusive
}

__global__ void scan3_kernel(const int* __restrict__ incl, const int* __restrict__ base,
                             const int* __restrict__ deg, int* __restrict__ rowPtr,
                             int* __restrict__ cursor, int n, int total) {
    int gid = blockIdx.x * 256 + threadIdx.x;
    if (gid < n) {
        int v = base[gid >> 8] + incl[gid] - deg[gid];  // exclusive
        rowPtr[gid] = v;
        cursor[gid] = v;
    } else if (gid == n) {
        rowPtr[n] = total;
    }
}

__global__ void fill_csr_kernel(const int* __restrict__ src, const int* __restrict__ dst,
                                int* __restrict__ cursor, int* __restrict__ colIdx, int E) {
    int i = blockIdx.x * blockDim.x + threadIdx.x;
    if (i < E) {
        int d = dst[i];
        int pos = atomicAdd(&cursor[d], 1);
        colIdx[pos] = src[i];
    }
}

// ---------------- graph segments ----------------
__global__ void graph_count_kernel(const int* __restrict__ batch, int* __restrict__ gcnt, int n) {
    int i = blockIdx.x * blockDim.x + threadIdx.x;
    if (i < n) atomicAdd(&gcnt[batch[i]], 1);
}

__global__ void scan_graphs_kernel(const int* __restrict__ cnt, int* __restrict__ start) {
    __shared__ int buf[2][512];
    int tid = threadIdx.x;  // exactly 512 threads
    int v = cnt[tid];
    buf[0][tid] = v;
    __syncthreads();
    int cur = 0;
    for (int off = 1; off < 512; off <<= 1) {
        buf[1 - cur][tid] = buf[cur][tid] + ((tid >= off) ? buf[cur][tid - off] : 0);
        cur ^= 1;
        __syncthreads();
    }
    start[tid] = buf[cur][tid] - v;
}

// ---------------- GEMM: Y(bf16) = act(X) @ W, X:(n,128) fp32, W:(128,128) fp32 ----
// optional fused input transform: x' = relu(x*scale[k] + shift[k])   (bn+relu)
#define GEMM_ROWS 32
__global__ __launch_bounds__(256) void gemm128_kernel(
    const float* __restrict__ X, const float* __restrict__ W,
    const float* __restrict__ scale, const float* __restrict__ shift,
    unsigned short* __restrict__ Y, int nrows)
{
    __shared__ float xs[GEMM_ROWS * D];   // 16 KB
    __shared__ float ws[D * D];           // 64 KB
    int tid = threadIdx.x;
    int row0 = blockIdx.x * GEMM_ROWS;
    bool fuse = (scale != nullptr);

#pragma unroll
    for (int i = 0; i < 64; ++i) ws[tid + i * 256] = W[tid + i * 256];

#pragma unroll
    for (int i = 0; i < GEMM_ROWS * D / 256; ++i) {
        int idx = tid + i * 256;
        int r = idx >> 7, k = idx & 127;
        int gr = row0 + r;
        float v = (gr < nrows) ? X[(size_t)gr * D + k] : 0.f;
        if (fuse) v = fmaxf(v * scale[k] + shift[k], 0.f);
        xs[idx] = v;
    }
    __syncthreads();

    int cg = tid & 31;          // cols cg, cg+32, cg+64, cg+96 (lane-striped: conflict-free)
    int rg = (tid >> 5) * 4;    // rows rg..rg+3
    float acc[4][4] = {};
#pragma unroll 4
    for (int k = 0; k < D; ++k) {
        float w0 = ws[k * D + cg];
        float w1 = ws[k * D + cg + 32];
        float w2 = ws[k * D + cg + 64];
        float w3 = ws[k * D + cg + 96];
#pragma unroll
        for (int j = 0; j < 4; ++j) {
            float xv = xs[(rg + j) * D + k];
            acc[j][0] += xv * w0;
            acc[j][1] += xv * w1;
            acc[j][2] += xv * w2;
            acc[j][3] += xv * w3;
        }
    }
#pragma unroll
    for (int j = 0; j < 4; ++j) {
        int gr = row0 + rg + j;
        if (gr < nrows) {
            unsigned short* yp = &Y[(size_t)gr * D];
            yp[cg]      = f2bf(acc[j][0]);
            yp[cg + 32] = f2bf(acc[j][1]);
            yp[cg + 64] = f2bf(acc[j][2]);
            yp[cg + 96] = f2bf(acc[j][3]);
        }
    }
}

// ---------------- aggregation: out = relu(dinv[v]*(sum_u dinv[u]*T[u] + dinv[v]*T[v]) + b) ----
// one wave per row; CSR, no atomics. T rows are bf16 (256 B), 64 lanes x 4 B.
__global__ __launch_bounds__(256) void aggregate_kernel(
    const unsigned int* __restrict__ T, const int* __restrict__ colIdx,
    const int* __restrict__ rowPtr, const float* __restrict__ dinv,
    const float* __restrict__ bias, float* __restrict__ outH, int n)
{
    int wid = threadIdx.x >> 6;
    int lane = threadIdx.x & 63;
    int row = blockIdx.x * 4 + wid;
    if (row >= n) return;

    float dr = dinv[row];
    unsigned int sv = T[(size_t)row * 64 + lane];
    float ax = dr * bf_lo(sv), ay = dr * bf_hi(sv);  // self loop (gets another *dr below)

    int s = rowPtr[row], e = rowPtr[row + 1];
    for (int j0 = s; j0 < e; j0 += 64) {
        int m = e - j0;
        if (m > 64) m = 64;
        int u = 0;
        float du = 0.f;
        if (lane < m) {
            u = colIdx[j0 + lane];
            du = dinv[u];
        }
        for (int t = 0; t < m; ++t) {
            int uu = __shfl(u, t);
            float duu = __shfl(du, t);
            unsigned int tw = T[(size_t)uu * 64 + lane];
            ax += duu * bf_lo(tw);
            ay += duu * bf_hi(tw);
        }
    }
    const float2* bp = (const float2*)bias;
    float2 b = bp[lane];
    float2 o;
    o.x = fmaxf(dr * ax + b.x, 0.f);
    o.y = fmaxf(dr * ay + b.y, 0.f);
    ((float2*)outH)[(size_t)row * 64 + lane] = o;
}

// ---------------- batchnorm stats ----------------
__global__ __launch_bounds__(256) void bn_stats_kernel(
    const float* __restrict__ H, int n, float* __restrict__ gsum, float* __restrict__ gsq)
{
    int tid = threadIdx.x;
    int col = tid & 127;
    float s = 0.f, s2 = 0.f;
    for (int row = blockIdx.x * 2 + (tid >> 7); row < n; row += gridDim.x * 2) {
        float v = H[(size_t)row * D + col];
        s += v;
        s2 += v * v;
    }
    __shared__ float sh[256], sh2[256];
    sh[tid] = s;
    sh2[tid] = s2;
    __syncthreads();
    if (tid < 128) {
        atomicAdd(&gsum[col], sh[tid] + sh[tid + 128]);
        atomicAdd(&gsq[col], sh2[tid] + sh2[tid + 128]);
    }
}

__global__ void bn_finalize_kernel(const float* __restrict__ gsum, const float* __restrict__ gsq,
                                   const float* __restrict__ gamma, const float* __restrict__ beta,
                                   float n, float* __restrict__ scale, float* __restrict__ shift)
{
    int c = threadIdx.x;  // 128
    float mu = gsum[c] / n;
    float var = gsq[c] / n - mu * mu;
    float sc = gamma[c] * rsqrtf(var + BN_EPS);
    scale[c] = sc;
    shift[c] = beta[c] - mu * sc;
}

// ---------------- pooling (fused bn2+relu) ----------------
__global__ __launch_bounds__(128) void pool_kernel(
    const float* __restrict__ H, const float* __restrict__ scale, const float* __restrict__ shift,
    const int* __restrict__ gstart, const int* __restrict__ gcnt, float* __restrict__ pooled)
{
    int g = blockIdx.x;
    int tid = threadIdx.x;  // 128
    int s = gstart[g], c = gcnt[g];
    float sc = scale[tid], sh = shift[tid];
    float a = 0.f;
    for (int i = 0; i < c; ++i) {
        float v = H[(size_t)(s + i) * D + tid];
        a += fmaxf(v * sc + sh, 0.f);
    }
    int cm = c > 1 ? c : 1;
    pooled[(size_t)g * D + tid] = a / (float)cm;
}

// ---------------- classifier + log_softmax ----------------
__global__ __launch_bounds__(64) void classify_kernel(
    const float* __restrict__ pooled, const float* __restrict__ fcw,
    const float* __restrict__ fcb, float* __restrict__ out)
{
    int g = blockIdx.x;
    int tid = threadIdx.x;  // 64
    __shared__ float prow[D];
    __shared__ float lg[C_CLASSES];
    prow[tid] = pooled[(size_t)g * D + tid];
    prow[tid + 64] = pooled[(size_t)g * D + 64 + tid];
    __syncthreads();
    if (tid < C_CLASSES) {
        float s = fcb[tid];
        for (int d = 0; d < D; ++d) s += prow[d] * fcw[d * C_CLASSES + tid];
        lg[tid] = s;
    }
    __syncthreads();
    if (tid == 0) {
        float m = -1e30f;
        for (int c = 0; c < C_CLASSES; ++c) m = fmaxf(m, lg[c]);
        float se = 0.f;
        for (int c = 0; c < C_CLASSES; ++c) se += expf(lg[c] - m);
        float lse = m + logf(se);
        for (int c = 0; c < C_CLASSES; ++c) out[(size_t)g * C_CLASSES + c] = lg[c] - lse;
    }
}

extern "C" void kernel_launch(void* const* d_in, const int* in_sizes, int n_in,
                              void* d_out, int out_size, void* d_ws, size_t ws_size,
                              hipStream_t stream) {
    const float* x   = (const float*)d_in[0];
    const int* ei    = (const int*)d_in[1];
    const int* batch = (const int*)d_in[2];
    const float* w1  = (const float*)d_in[3];
    const float* b1  = (const float*)d_in[4];
    const float* w2  = (const float*)d_in[5];
    const float* b2  = (const float*)d_in[6];
    const float* w3  = (const float*)d_in[7];
    const float* b3  = (const float*)d_in[8];
    const float* g1  = (const float*)d_in[9];
    const float* be1 = (const float*)d_in[10];
    const float* g2  = (const float*)d_in[11];
    const float* be2 = (const float*)d_in[12];
    const float* fcw = (const float*)d_in[13];
    const float* fcb = (const float*)d_in[14];

    const int N = in_sizes[0] / D;
    const int E = in_sizes[1] / 2;
    const int* src = ei;
    const int* dst = ei + E;

    // workspace carve (256B aligned)
    char* p = (char*)d_ws;
    auto alloc = [&](size_t bytes) -> void* {
        void* r = (void*)p;
        p += (bytes + 255) & ~(size_t)255;
        return r;
    };
    int*   degi    = (int*)alloc((size_t)N * 4);
    float* dinv    = (float*)alloc((size_t)N * 4);
    int*   rowPtr  = (int*)alloc((size_t)(N + 1) * 4);
    int*   cursor  = (int*)alloc((size_t)N * 4);
    int*   incl    = (int*)alloc((size_t)N * 4);
    int*   partials= (int*)alloc(512 * 4);
    int*   colIdx  = (int*)alloc((size_t)E * 4);
    int*   gcnt    = (int*)alloc(G_GRAPHS * 4);
    int*   gstart  = (int*)alloc(G_GRAPHS * 4);
    float* statsacc= (float*)alloc(4 * D * 4);   // gsum1, gsq1, gsum2, gsq2
    float* gsum1 = statsacc, *gsq1 = statsacc + D, *gsum2 = statsacc + 2 * D, *gsq2 = statsacc + 3 * D;
    float* sc1     = (float*)alloc(D * 4);
    float* sh1     = (float*)alloc(D * 4);
    float* sc2     = (float*)alloc(D * 4);
    float* sh2     = (float*)alloc(D * 4);
    float* pooled  = (float*)alloc((size_t)G_GRAPHS * D * 4);
    unsigned short* tmp = (unsigned short*)alloc((size_t)N * D * 2);  // bf16
    float* hbuf    = (float*)alloc((size_t)N * D * 4);

    hipMemsetAsync(degi, 0, (size_t)N * 4, stream);
    hipMemsetAsync(gcnt, 0, G_GRAPHS * 4, stream);
    hipMemsetAsync(statsacc, 0, 4 * D * 4, stream);

    const int NB = (N + 255) / 256;  // scan chunks

    // graph structure
    deg_count_kernel<<<(E + 255) / 256, 256, 0, stream>>>(dst, degi, E);
    deg_to_dinv_kernel<<<NB, 256, 0, stream>>>(degi, dinv, N);
    scan1_kernel<<<NB, 256, 0, stream>>>(degi, incl, partials, N);
    scan2_kernel<<<1, 512, 0, stream>>>(partials, NB);
    scan3_kernel<<<NB, 256, 0, stream>>>(incl, partials, degi, rowPtr, cursor, N, E);
    fill_csr_kernel<<<(E + 255) / 256, 256, 0, stream>>>(src, dst, cursor, colIdx, E);
    graph_count_kernel<<<NB, 256, 0, stream>>>(batch, gcnt, N);
    scan_graphs_kernel<<<1, 512, 0, stream>>>(gcnt, gstart);

    const int GB = (N + GEMM_ROWS - 1) / GEMM_ROWS;
    const int AB = (N + 3) / 4;

    // layer 1: h = relu(agg(x@w1) + b1)
    gemm128_kernel<<<GB, 256, 0, stream>>>(x, w1, nullptr, nullptr, tmp, N);
    aggregate_kernel<<<AB, 256, 0, stream>>>((const unsigned int*)tmp, colIdx, rowPtr, dinv, b1, hbuf, N);
    // layer 2
    gemm128_kernel<<<GB, 256, 0, stream>>>(hbuf, w2, nullptr, nullptr, tmp, N);
    aggregate_kernel<<<AB, 256, 0, stream>>>((const unsigned int*)tmp, colIdx, rowPtr, dinv, b2, hbuf, N);
    // bn1 stats on h2
    bn_stats_kernel<<<512, 256, 0, stream>>>(hbuf, N, gsum1, gsq1);
    bn_finalize_kernel<<<1, 128, 0, stream>>>(gsum1, gsq1, g1, be1, (float)N, sc1, sh1);
    // layer 3 (bn1+relu fused into gemm input)
    gemm128_kernel<<<GB, 256, 0, stream>>>(hbuf, w3, sc1, sh1, tmp, N);
    aggregate_kernel<<<AB, 256, 0, stream>>>((const unsigned int*)tmp, colIdx, rowPtr, dinv, b3, hbuf, N);
    // bn2 stats on h3
    bn_stats_kernel<<<512, 256, 0, stream>>>(hbuf, N, gsum2, gsq2);
    bn_finalize_kernel<<<1, 128, 0, stream>>>(gsum2, gsq2, g2, be2, (float)N, sc2, sh2);
    // pool (bn2+relu fused) + classify
    pool_kernel<<<G_GRAPHS, 128, 0, stream>>>(hbuf, sc2, sh2, gstart, gcnt, pooled);
    classify_kernel<<<G_GRAPHS, 64, 0, stream>>>(pooled, fcw, fcb, (float*)d_out);
}

// Round 3
// 963.133 us; speedup vs baseline: 1.2284x; 1.1483x over previous
//
#include <hip/hip_runtime.h>
#include <hip/hip_bf16.h>
#include <math.h>

#define D 128
#define G_GRAPHS 512
#define C_CLASSES 10
#define BN_EPS 1e-5f
#define NBUCK_MAX 512     // supports N <= 131072 (bucket = node >> 8)
#define EDGE_CHUNK 4096
#define EPT 16            // EDGE_CHUNK / 256

__device__ __forceinline__ float bf_lo(unsigned int v) { return __uint_as_float(v << 16); }
__device__ __forceinline__ float bf_hi(unsigned int v) { return __uint_as_float(v & 0xffff0000u); }
__device__ __forceinline__ unsigned short f2bf(float f) {
    union { float f; unsigned int u; } x; x.f = f;
    unsigned int r = x.u + 0x7fff + ((x.u >> 16) & 1);  // RN-even
    return (unsigned short)(r >> 16);
}

// ============ CSR build: two-level counting sort (no random 4B scatter) ============

// pass 1: per-block LDS histogram of dst>>8, flush to global bucketCnt
__global__ __launch_bounds__(256) void bucket_hist_kernel(
    const int* __restrict__ dst, int* __restrict__ bucketCnt, int E, int nbuck)
{
    __shared__ int h[NBUCK_MAX];
    int tid = threadIdx.x;
    for (int i = tid; i < NBUCK_MAX; i += 256) h[i] = 0;
    __syncthreads();
    for (int i = blockIdx.x * 256 + tid; i < E; i += gridDim.x * 256)
        atomicAdd(&h[dst[i] >> 8], 1);
    __syncthreads();
    for (int i = tid; i < nbuck; i += 256)
        if (h[i]) atomicAdd(&bucketCnt[i], h[i]);
}

// pass 2: exclusive scan of bucket counts (single block, 512 threads)
__global__ void scan_buckets_kernel(
    const int* __restrict__ bucketCnt, int* __restrict__ bucketBase,
    int* __restrict__ bucketCursor, int* __restrict__ rowPtr, int nbuck, int N, int E)
{
    __shared__ int buf[2][512];
    int tid = threadIdx.x;
    int v = (tid < nbuck) ? bucketCnt[tid] : 0;
    buf[0][tid] = v;
    __syncthreads();
    int cur = 0;
    for (int off = 1; off < 512; off <<= 1) {
        buf[1 - cur][tid] = buf[cur][tid] + ((tid >= off) ? buf[cur][tid - off] : 0);
        cur ^= 1;
        __syncthreads();
    }
    if (tid < nbuck) {
        int b = buf[cur][tid] - v;  // exclusive
        bucketBase[tid] = b;
        bucketCursor[tid] = b;
    }
    if (tid == 0) { bucketBase[nbuck] = E; rowPtr[N] = E; }
}

// pass 3: scatter (src,dst) pairs into bucket-grouped order.
// block-local LDS ranks -> one global atomic per (block,bucket) -> ~84B write runs
__global__ __launch_bounds__(256) void scatter_pairs_kernel(
    const int* __restrict__ src, const int* __restrict__ dst,
    int* __restrict__ bucketCursor, uint2* __restrict__ pairs, int E)
{
    __shared__ int h[NBUCK_MAX];
    __shared__ int base[NBUCK_MAX];
    int tid = threadIdx.x;
    int e0 = blockIdx.x * EDGE_CHUNK;
    for (int i = tid; i < NBUCK_MAX; i += 256) h[i] = 0;
    __syncthreads();
    int s[EPT], d[EPT], r[EPT];
#pragma unroll
    for (int j = 0; j < EPT; ++j) {
        int i = e0 + j * 256 + tid;
        if (i < E) {
            s[j] = src[i];
            d[j] = dst[i];
            r[j] = atomicAdd(&h[d[j] >> 8], 1);
        } else {
            d[j] = -1;
        }
    }
    __syncthreads();
    for (int i = tid; i < NBUCK_MAX; i += 256)
        if (h[i]) base[i] = atomicAdd(&bucketCursor[i], h[i]);
    __syncthreads();
#pragma unroll
    for (int j = 0; j < EPT; ++j) {
        if (d[j] >= 0) {
            int b = d[j] >> 8;
            pairs[base[b] + r[j]] = make_uint2((unsigned)s[j], (unsigned)d[j]);
        }
    }
}

// pass 4: one block per bucket — LDS counting sort over ~4k edges.
// emits rowPtr, dinv, colIdx; all colIdx writes within a 16KB L2-hot window.
__global__ __launch_bounds__(256) void bucket_sort_kernel(
    const uint2* __restrict__ pairs, const int* __restrict__ bucketBase,
    int* __restrict__ colIdx, int* __restrict__ rowPtr, float* __restrict__ dinv, int N)
{
    __shared__ int h[256];
    __shared__ int cur[256];
    __shared__ int sbuf[2][256];
    int tid = threadIdx.x;
    int b = blockIdx.x;
    int s = bucketBase[b], e = bucketBase[b + 1];
    h[tid] = 0;
    __syncthreads();
    for (int i = s + tid; i < e; i += 256)
        atomicAdd(&h[pairs[i].y & 255], 1);
    __syncthreads();
    int cnt = h[tid];
    sbuf[0][tid] = cnt;
    __syncthreads();
    int c = 0;
    for (int off = 1; off < 256; off <<= 1) {
        sbuf[1 - c][tid] = sbuf[c][tid] + ((tid >= off) ? sbuf[c][tid - off] : 0);
        c ^= 1;
        __syncthreads();
    }
    int excl = sbuf[c][tid] - cnt;
    int v = b * 256 + tid;
    if (v < N) {
        rowPtr[v] = s + excl;
        dinv[v] = rsqrtf((float)(cnt + 1));  // +1 self loop
    }
    cur[tid] = s + excl;
    __syncthreads();
    for (int i = s + tid; i < e; i += 256) {
        uint2 p = pairs[i];
        int pos = atomicAdd(&cur[p.y & 255], 1);
        colIdx[pos] = (int)p.x;
    }
}

// ---------------- graph segments ----------------
__global__ void graph_count_kernel(const int* __restrict__ batch, int* __restrict__ gcnt, int n) {
    int i = blockIdx.x * blockDim.x + threadIdx.x;
    if (i < n) atomicAdd(&gcnt[batch[i]], 1);
}

__global__ void scan_graphs_kernel(const int* __restrict__ cnt, int* __restrict__ start) {
    __shared__ int buf[2][512];
    int tid = threadIdx.x;  // exactly 512 threads
    int v = cnt[tid];
    buf[0][tid] = v;
    __syncthreads();
    int cur = 0;
    for (int off = 1; off < 512; off <<= 1) {
        buf[1 - cur][tid] = buf[cur][tid] + ((tid >= off) ? buf[cur][tid - off] : 0);
        cur ^= 1;
        __syncthreads();
    }
    start[tid] = buf[cur][tid] - v;
}

// ---------------- GEMM: Y(bf16) = act(X) @ W, X:(n,128) fp32, W:(128,128) fp32 ----
#define GEMM_ROWS 32
__global__ __launch_bounds__(256) void gemm128_kernel(
    const float* __restrict__ X, const float* __restrict__ W,
    const float* __restrict__ scale, const float* __restrict__ shift,
    unsigned short* __restrict__ Y, int nrows)
{
    __shared__ float xs[GEMM_ROWS * D];   // 16 KB
    __shared__ float ws[D * D];           // 64 KB
    int tid = threadIdx.x;
    int row0 = blockIdx.x * GEMM_ROWS;
    bool fuse = (scale != nullptr);

#pragma unroll
    for (int i = 0; i < 64; ++i) ws[tid + i * 256] = W[tid + i * 256];

#pragma unroll
    for (int i = 0; i < GEMM_ROWS * D / 256; ++i) {
        int idx = tid + i * 256;
        int r = idx >> 7, k = idx & 127;
        int gr = row0 + r;
        float v = (gr < nrows) ? X[(size_t)gr * D + k] : 0.f;
        if (fuse) v = fmaxf(v * scale[k] + shift[k], 0.f);
        xs[idx] = v;
    }
    __syncthreads();

    int cg = tid & 31;
    int rg = (tid >> 5) * 4;
    float acc[4][4] = {};
#pragma unroll 4
    for (int k = 0; k < D; ++k) {
        float w0 = ws[k * D + cg];
        float w1 = ws[k * D + cg + 32];
        float w2 = ws[k * D + cg + 64];
        float w3 = ws[k * D + cg + 96];
#pragma unroll
        for (int j = 0; j < 4; ++j) {
            float xv = xs[(rg + j) * D + k];
            acc[j][0] += xv * w0;
            acc[j][1] += xv * w1;
            acc[j][2] += xv * w2;
            acc[j][3] += xv * w3;
        }
    }
#pragma unroll
    for (int j = 0; j < 4; ++j) {
        int gr = row0 + rg + j;
        if (gr < nrows) {
            unsigned short* yp = &Y[(size_t)gr * D];
            yp[cg]      = f2bf(acc[j][0]);
            yp[cg + 32] = f2bf(acc[j][1]);
            yp[cg + 64] = f2bf(acc[j][2]);
            yp[cg + 96] = f2bf(acc[j][3]);
        }
    }
}

// ---------------- aggregation (bf16 gather rows) ----------------
__global__ __launch_bounds__(256) void aggregate_kernel(
    const unsigned int* __restrict__ T, const int* __restrict__ colIdx,
    const int* __restrict__ rowPtr, const float* __restrict__ dinv,
    const float* __restrict__ bias, float* __restrict__ outH, int n)
{
    int wid = threadIdx.x >> 6;
    int lane = threadIdx.x & 63;
    int row = blockIdx.x * 4 + wid;
    if (row >= n) return;

    float dr = dinv[row];
    unsigned int sv = T[(size_t)row * 64 + lane];
    float ax = dr * bf_lo(sv), ay = dr * bf_hi(sv);

    int s = rowPtr[row], e = rowPtr[row + 1];
    for (int j0 = s; j0 < e; j0 += 64) {
        int m = e - j0;
        if (m > 64) m = 64;
        int u = 0;
        float du = 0.f;
        if (lane < m) {
            u = colIdx[j0 + lane];
            du = dinv[u];
        }
        for (int t = 0; t < m; ++t) {
            int uu = __shfl(u, t);
            float duu = __shfl(du, t);
            unsigned int tw = T[(size_t)uu * 64 + lane];
            ax += duu * bf_lo(tw);
            ay += duu * bf_hi(tw);
        }
    }
    const float2* bp = (const float2*)bias;
    float2 b = bp[lane];
    float2 o;
    o.x = fmaxf(dr * ax + b.x, 0.f);
    o.y = fmaxf(dr * ay + b.y, 0.f);
    ((float2*)outH)[(size_t)row * 64 + lane] = o;
}

// ---------------- batchnorm stats ----------------
__global__ __launch_bounds__(256) void bn_stats_kernel(
    const float* __restrict__ H, int n, float* __restrict__ gsum, float* __restrict__ gsq)
{
    int tid = threadIdx.x;
    int col = tid & 127;
    float s = 0.f, s2 = 0.f;
    for (int row = blockIdx.x * 2 + (tid >> 7); row < n; row += gridDim.x * 2) {
        float v = H[(size_t)row * D + col];
        s += v;
        s2 += v * v;
    }
    __shared__ float sh[256], sh2[256];
    sh[tid] = s;
    sh2[tid] = s2;
    __syncthreads();
    if (tid < 128) {
        atomicAdd(&gsum[col], sh[tid] + sh[tid + 128]);
        atomicAdd(&gsq[col], sh2[tid] + sh2[tid + 128]);
    }
}

__global__ void bn_finalize_kernel(const float* __restrict__ gsum, const float* __restrict__ gsq,
                                   const float* __restrict__ gamma, const float* __restrict__ beta,
                                   float n, float* __restrict__ scale, float* __restrict__ shift)
{
    int c = threadIdx.x;  // 128
    float mu = gsum[c] / n;
    float var = gsq[c] / n - mu * mu;
    float sc = gamma[c] * rsqrtf(var + BN_EPS);
    scale[c] = sc;
    shift[c] = beta[c] - mu * sc;
}

// ---------------- pooling (fused bn2+relu) ----------------
__global__ __launch_bounds__(128) void pool_kernel(
    const float* __restrict__ H, const float* __restrict__ scale, const float* __restrict__ shift,
    const int* __restrict__ gstart, const int* __restrict__ gcnt, float* __restrict__ pooled)
{
    int g = blockIdx.x;
    int tid = threadIdx.x;  // 128
    int s = gstart[g], c = gcnt[g];
    float sc = scale[tid], sh = shift[tid];
    float a = 0.f;
    for (int i = 0; i < c; ++i) {
        float v = H[(size_t)(s + i) * D + tid];
        a += fmaxf(v * sc + sh, 0.f);
    }
    int cm = c > 1 ? c : 1;
    pooled[(size_t)g * D + tid] = a / (float)cm;
}

// ---------------- classifier + log_softmax ----------------
__global__ __launch_bounds__(64) void classify_kernel(
    const float* __restrict__ pooled, const float* __restrict__ fcw,
    const float* __restrict__ fcb, float* __restrict__ out)
{
    int g = blockIdx.x;
    int tid = threadIdx.x;  // 64
    __shared__ float prow[D];
    __shared__ float lg[C_CLASSES];
    prow[tid] = pooled[(size_t)g * D + tid];
    prow[tid + 64] = pooled[(size_t)g * D + 64 + tid];
    __syncthreads();
    if (tid < C_CLASSES) {
        float s = fcb[tid];
        for (int d = 0; d < D; ++d) s += prow[d] * fcw[d * C_CLASSES + tid];
        lg[tid] = s;
    }
    __syncthreads();
    if (tid == 0) {
        float m = -1e30f;
        for (int c = 0; c < C_CLASSES; ++c) m = fmaxf(m, lg[c]);
        float se = 0.f;
        for (int c = 0; c < C_CLASSES; ++c) se += expf(lg[c] - m);
        float lse = m + logf(se);
        for (int c = 0; c < C_CLASSES; ++c) out[(size_t)g * C_CLASSES + c] = lg[c] - lse;
    }
}

extern "C" void kernel_launch(void* const* d_in, const int* in_sizes, int n_in,
                              void* d_out, int out_size, void* d_ws, size_t ws_size,
                              hipStream_t stream) {
    const float* x   = (const float*)d_in[0];
    const int* ei    = (const int*)d_in[1];
    const int* batch = (const int*)d_in[2];
    const float* w1  = (const float*)d_in[3];
    const float* b1  = (const float*)d_in[4];
    const float* w2  = (const float*)d_in[5];
    const float* b2  = (const float*)d_in[6];
    const float* w3  = (const float*)d_in[7];
    const float* b3  = (const float*)d_in[8];
    const float* g1  = (const float*)d_in[9];
    const float* be1 = (const float*)d_in[10];
    const float* g2  = (const float*)d_in[11];
    const float* be2 = (const float*)d_in[12];
    const float* fcw = (const float*)d_in[13];
    const float* fcb = (const float*)d_in[14];

    const int N = in_sizes[0] / D;
    const int E = in_sizes[1] / 2;
    const int* src = ei;
    const int* dst = ei + E;
    const int nbuck = (N + 255) >> 8;   // <= NBUCK_MAX for N <= 131072

    // workspace carve (256B aligned)
    char* p = (char*)d_ws;
    auto alloc = [&](size_t bytes) -> void* {
        void* r = (void*)p;
        p += (bytes + 255) & ~(size_t)255;
        return r;
    };
    float* dinv     = (float*)alloc((size_t)N * 4);
    int*   rowPtr   = (int*)alloc((size_t)(N + 1) * 4);
    int*   colIdx   = (int*)alloc((size_t)E * 4);
    uint2* pairs    = (uint2*)alloc((size_t)E * 8);
    int*   bucketCnt    = (int*)alloc(NBUCK_MAX * 4);
    int*   bucketBase   = (int*)alloc((NBUCK_MAX + 1) * 4);
    int*   bucketCursor = (int*)alloc(NBUCK_MAX * 4);
    int*   gcnt    = (int*)alloc(G_GRAPHS * 4);
    int*   gstart  = (int*)alloc(G_GRAPHS * 4);
    float* statsacc= (float*)alloc(4 * D * 4);   // gsum1, gsq1, gsum2, gsq2
    float* gsum1 = statsacc, *gsq1 = statsacc + D, *gsum2 = statsacc + 2 * D, *gsq2 = statsacc + 3 * D;
    float* sc1     = (float*)alloc(D * 4);
    float* sh1     = (float*)alloc(D * 4);
    float* sc2     = (float*)alloc(D * 4);
    float* sh2     = (float*)alloc(D * 4);
    float* pooled  = (float*)alloc((size_t)G_GRAPHS * D * 4);
    unsigned short* tmp = (unsigned short*)alloc((size_t)N * D * 2);  // bf16
    float* hbuf    = (float*)alloc((size_t)N * D * 4);

    hipMemsetAsync(bucketCnt, 0, NBUCK_MAX * 4, stream);
    hipMemsetAsync(gcnt, 0, G_GRAPHS * 4, stream);
    hipMemsetAsync(statsacc, 0, 4 * D * 4, stream);

    // ---- graph structure: two-level counting sort ----
    bucket_hist_kernel<<<512, 256, 0, stream>>>(dst, bucketCnt, E, nbuck);
    scan_buckets_kernel<<<1, 512, 0, stream>>>(bucketCnt, bucketBase, bucketCursor, rowPtr, nbuck, N, E);
    scatter_pairs_kernel<<<(E + EDGE_CHUNK - 1) / EDGE_CHUNK, 256, 0, stream>>>(src, dst, bucketCursor, pairs, E);
    bucket_sort_kernel<<<nbuck, 256, 0, stream>>>(pairs, bucketBase, colIdx, rowPtr, dinv, N);
    graph_count_kernel<<<(N + 255) / 256, 256, 0, stream>>>(batch, gcnt, N);
    scan_graphs_kernel<<<1, 512, 0, stream>>>(gcnt, gstart);

    const int GB = (N + GEMM_ROWS - 1) / GEMM_ROWS;
    const int AB = (N + 3) / 4;

    // layer 1: h = relu(agg(x@w1) + b1)
    gemm128_kernel<<<GB, 256, 0, stream>>>(x, w1, nullptr, nullptr, tmp, N);
    aggregate_kernel<<<AB, 256, 0, stream>>>((const unsigned int*)tmp, colIdx, rowPtr, dinv, b1, hbuf, N);
    // layer 2
    gemm128_kernel<<<GB, 256, 0, stream>>>(hbuf, w2, nullptr, nullptr, tmp, N);
    aggregate_kernel<<<AB, 256, 0, stream>>>((const unsigned int*)tmp, colIdx, rowPtr, dinv, b2, hbuf, N);
    // bn1 stats on h2
    bn_stats_kernel<<<512, 256, 0, stream>>>(hbuf, N, gsum1, gsq1);
    bn_finalize_kernel<<<1, 128, 0, stream>>>(gsum1, gsq1, g1, be1, (float)N, sc1, sh1);
    // layer 3 (bn1+relu fused into gemm input)
    gemm128_kernel<<<GB, 256, 0, stream>>>(hbuf, w3, sc1, sh1, tmp, N);
    aggregate_kernel<<<AB, 256, 0, stream>>>((const unsigned int*)tmp, colIdx, rowPtr, dinv, b3, hbuf, N);
    // bn2 stats on h3
    bn_stats_kernel<<<512, 256, 0, stream>>>(hbuf, N, gsum2, gsq2);
    bn_finalize_kernel<<<1, 128, 0, stream>>>(gsum2, gsq2, g2, be2, (float)N, sc2, sh2);
    // pool (bn2+relu fused) + classify
    pool_kernel<<<G_GRAPHS, 128, 0, stream>>>(hbuf, sc2, sh2, gstart, gcnt, pooled);
    classify_kernel<<<G_GRAPHS, 64, 0, stream>>>(pooled, fcw, fcb, (float*)d_out);
}

// Round 4
// 849.004 us; speedup vs baseline: 1.3936x; 1.1344x over previous
//
#include <hip/hip_runtime.h>
#include <hip/hip_bf16.h>
#include <math.h>

#define D 128
#define G_GRAPHS 512
#define C_CLASSES 10
#define BN_EPS 1e-5f
#define NBUCK_MAX 512     // supports N <= 131072 (bucket = node >> 8)
#define EDGE_CHUNK 4096
#define EPT 16            // EDGE_CHUNK / 256

__device__ __forceinline__ float bf_lo(unsigned int v) { return __uint_as_float(v << 16); }
__device__ __forceinline__ float bf_hi(unsigned int v) { return __uint_as_float(v & 0xffff0000u); }
__device__ __forceinline__ unsigned short f2bf(float f) {
    union { float f; unsigned int u; } x; x.f = f;
    unsigned int r = x.u + 0x7fff + ((x.u >> 16) & 1);  // RN-even
    return (unsigned short)(r >> 16);
}

// ============ CSR build: two-level counting sort ============

__global__ __launch_bounds__(256) void bucket_hist_kernel(
    const int* __restrict__ dst, int* __restrict__ bucketCnt, int E, int nbuck)
{
    __shared__ int h[NBUCK_MAX];
    int tid = threadIdx.x;
    for (int i = tid; i < NBUCK_MAX; i += 256) h[i] = 0;
    __syncthreads();
    for (int i = blockIdx.x * 256 + tid; i < E; i += gridDim.x * 256)
        atomicAdd(&h[dst[i] >> 8], 1);
    __syncthreads();
    for (int i = tid; i < nbuck; i += 256)
        if (h[i]) atomicAdd(&bucketCnt[i], h[i]);
}

__global__ void scan_buckets_kernel(
    const int* __restrict__ bucketCnt, int* __restrict__ bucketBase,
    int* __restrict__ bucketCursor, int* __restrict__ rowPtr, int nbuck, int N, int E)
{
    __shared__ int buf[2][512];
    int tid = threadIdx.x;
    int v = (tid < nbuck) ? bucketCnt[tid] : 0;
    buf[0][tid] = v;
    __syncthreads();
    int cur = 0;
    for (int off = 1; off < 512; off <<= 1) {
        buf[1 - cur][tid] = buf[cur][tid] + ((tid >= off) ? buf[cur][tid - off] : 0);
        cur ^= 1;
        __syncthreads();
    }
    if (tid < nbuck) {
        int b = buf[cur][tid] - v;  // exclusive
        bucketBase[tid] = b;
        bucketCursor[tid] = b;
    }
    if (tid == 0) { bucketBase[nbuck] = E; rowPtr[N] = E; }
}

__global__ __launch_bounds__(256) void scatter_pairs_kernel(
    const int* __restrict__ src, const int* __restrict__ dst,
    int* __restrict__ bucketCursor, uint2* __restrict__ pairs, int E)
{
    __shared__ int h[NBUCK_MAX];
    __shared__ int base[NBUCK_MAX];
    int tid = threadIdx.x;
    int e0 = blockIdx.x * EDGE_CHUNK;
    for (int i = tid; i < NBUCK_MAX; i += 256) h[i] = 0;
    __syncthreads();
    int s[EPT], d[EPT], r[EPT];
#pragma unroll
    for (int j = 0; j < EPT; ++j) {
        int i = e0 + j * 256 + tid;
        if (i < E) {
            s[j] = src[i];
            d[j] = dst[i];
            r[j] = atomicAdd(&h[d[j] >> 8], 1);
        } else {
            d[j] = -1;
        }
    }
    __syncthreads();
    for (int i = tid; i < NBUCK_MAX; i += 256)
        if (h[i]) base[i] = atomicAdd(&bucketCursor[i], h[i]);
    __syncthreads();
#pragma unroll
    for (int j = 0; j < EPT; ++j) {
        if (d[j] >= 0) {
            int b = d[j] >> 8;
            pairs[base[b] + r[j]] = make_uint2((unsigned)s[j], (unsigned)d[j]);
        }
    }
}

__global__ __launch_bounds__(256) void bucket_sort_kernel(
    const uint2* __restrict__ pairs, const int* __restrict__ bucketBase,
    int* __restrict__ colIdx, int* __restrict__ rowPtr, float* __restrict__ dinv, int N)
{
    __shared__ int h[256];
    __shared__ int cur[256];
    __shared__ int sbuf[2][256];
    int tid = threadIdx.x;
    int b = blockIdx.x;
    int s = bucketBase[b], e = bucketBase[b + 1];
    h[tid] = 0;
    __syncthreads();
    for (int i = s + tid; i < e; i += 256)
        atomicAdd(&h[pairs[i].y & 255], 1);
    __syncthreads();
    int cnt = h[tid];
    sbuf[0][tid] = cnt;
    __syncthreads();
    int c = 0;
    for (int off = 1; off < 256; off <<= 1) {
        sbuf[1 - c][tid] = sbuf[c][tid] + ((tid >= off) ? sbuf[c][tid - off] : 0);
        c ^= 1;
        __syncthreads();
    }
    int excl = sbuf[c][tid] - cnt;
    int v = b * 256 + tid;
    if (v < N) {
        rowPtr[v] = s + excl;
        dinv[v] = rsqrtf((float)(cnt + 1));  // +1 self loop
    }
    cur[tid] = s + excl;
    __syncthreads();
    for (int i = s + tid; i < e; i += 256) {
        uint2 p = pairs[i];
        int pos = atomicAdd(&cur[p.y & 255], 1);
        colIdx[pos] = (int)p.x;
    }
}

// ---------------- graph segments ----------------
__global__ void graph_count_kernel(const int* __restrict__ batch, int* __restrict__ gcnt, int n) {
    int i = blockIdx.x * blockDim.x + threadIdx.x;
    if (i < n) atomicAdd(&gcnt[batch[i]], 1);
}

__global__ void scan_graphs_kernel(const int* __restrict__ cnt, int* __restrict__ start) {
    __shared__ int buf[2][512];
    int tid = threadIdx.x;  // exactly 512 threads
    int v = cnt[tid];
    buf[0][tid] = v;
    __syncthreads();
    int cur = 0;
    for (int off = 1; off < 512; off <<= 1) {
        buf[1 - cur][tid] = buf[cur][tid] + ((tid >= off) ? buf[cur][tid - off] : 0);
        cur ^= 1;
        __syncthreads();
    }
    start[tid] = buf[cur][tid] - v;
}

// ---------------- GEMM: Y(bf16) = act(X) @ W ----------------
#define GEMM_ROWS 32
__global__ __launch_bounds__(256) void gemm128_kernel(
    const float* __restrict__ X, const float* __restrict__ W,
    const float* __restrict__ scale, const float* __restrict__ shift,
    unsigned short* __restrict__ Y, int nrows)
{
    __shared__ float xs[GEMM_ROWS * D];   // 16 KB
    __shared__ float ws[D * D];           // 64 KB
    int tid = threadIdx.x;
    int row0 = blockIdx.x * GEMM_ROWS;
    bool fuse = (scale != nullptr);

#pragma unroll
    for (int i = 0; i < 64; ++i) ws[tid + i * 256] = W[tid + i * 256];

#pragma unroll
    for (int i = 0; i < GEMM_ROWS * D / 256; ++i) {
        int idx = tid + i * 256;
        int r = idx >> 7, k = idx & 127;
        int gr = row0 + r;
        float v = (gr < nrows) ? X[(size_t)gr * D + k] : 0.f;
        if (fuse) v = fmaxf(v * scale[k] + shift[k], 0.f);
        xs[idx] = v;
    }
    __syncthreads();

    int cg = tid & 31;
    int rg = (tid >> 5) * 4;
    float acc[4][4] = {};
#pragma unroll 4
    for (int k = 0; k < D; ++k) {
        float w0 = ws[k * D + cg];
        float w1 = ws[k * D + cg + 32];
        float w2 = ws[k * D + cg + 64];
        float w3 = ws[k * D + cg + 96];
#pragma unroll
        for (int j = 0; j < 4; ++j) {
            float xv = xs[(rg + j) * D + k];
            acc[j][0] += xv * w0;
            acc[j][1] += xv * w1;
            acc[j][2] += xv * w2;
            acc[j][3] += xv * w3;
        }
    }
#pragma unroll
    for (int j = 0; j < 4; ++j) {
        int gr = row0 + rg + j;
        if (gr < nrows) {
            unsigned short* yp = &Y[(size_t)gr * D];
            yp[cg]      = f2bf(acc[j][0]);
            yp[cg + 32] = f2bf(acc[j][1]);
            yp[cg + 64] = f2bf(acc[j][2]);
            yp[cg + 96] = f2bf(acc[j][3]);
        }
    }
}

// ---------------- aggregation v2: 4 edges/iter, dwordx4 gathers ----------------
// wave = 4 edge-groups x 16 lanes; each group covers a full 256B bf16 row.
// lane: fg = lane&15 (uint4 index in row), eg = lane>>4 (edge subgroup).
__global__ __launch_bounds__(256) void aggregate_kernel(
    const uint4* __restrict__ T, const int* __restrict__ colIdx,
    const int* __restrict__ rowPtr, const float* __restrict__ dinv,
    const float* __restrict__ bias, float* __restrict__ outH, int n)
{
    int wid = threadIdx.x >> 6;
    int lane = threadIdx.x & 63;
    int row = blockIdx.x * 4 + wid;
    if (row >= n) return;
    int fg = lane & 15;
    int eg = lane >> 4;

    float dr = dinv[row];
    float acc[8] = {};

    // self loop: only group 0 (to avoid 4x replication after butterfly)
    if (eg == 0) {
        uint4 sv = T[(size_t)row * 16 + fg];
        acc[0] = dr * bf_lo(sv.x); acc[1] = dr * bf_hi(sv.x);
        acc[2] = dr * bf_lo(sv.y); acc[3] = dr * bf_hi(sv.y);
        acc[4] = dr * bf_lo(sv.z); acc[5] = dr * bf_hi(sv.z);
        acc[6] = dr * bf_lo(sv.w); acc[7] = dr * bf_hi(sv.w);
    }

    int s = rowPtr[row], e = rowPtr[row + 1];
    for (int j0 = s; j0 < e; j0 += 64) {
        int m = e - j0;
        if (m > 64) m = 64;
        int u = row;        // safe address for inactive lanes
        float du = 0.f;     // zero weight for inactive lanes
        if (lane < m) {
            u = colIdx[j0 + lane];
            du = dinv[u];
        }
        int nt = (m + 3) >> 2;
        for (int t = 0; t < nt; ++t) {
            int idx = t * 4 + eg;           // edge slot within chunk (always < 64)
            int uu = __shfl(u, idx);
            float duu = __shfl(du, idx);    // 0 beyond m -> no contribution
            uint4 tw = T[(size_t)uu * 16 + fg];
            acc[0] += duu * bf_lo(tw.x); acc[1] += duu * bf_hi(tw.x);
            acc[2] += duu * bf_lo(tw.y); acc[3] += duu * bf_hi(tw.y);
            acc[4] += duu * bf_lo(tw.z); acc[5] += duu * bf_hi(tw.z);
            acc[6] += duu * bf_lo(tw.w); acc[7] += duu * bf_hi(tw.w);
        }
    }

    // merge the 4 edge-groups: butterfly over lane bits 4,5
#pragma unroll
    for (int off = 16; off < 64; off <<= 1) {
#pragma unroll
        for (int i = 0; i < 8; ++i) acc[i] += __shfl_xor(acc[i], off);
    }

    // each lane writes float2: features fg*8 + eg*2, +1
    const float2* bp = (const float2*)bias;
    int pidx = fg * 4 + eg;
    float2 b = bp[pidx];
    float2 o;
    o.x = fmaxf(dr * acc[eg * 2] + b.x, 0.f);
    o.y = fmaxf(dr * acc[eg * 2 + 1] + b.y, 0.f);
    ((float2*)outH)[(size_t)row * 64 + pidx] = o;
}

// ---------------- batchnorm stats ----------------
__global__ __launch_bounds__(256) void bn_stats_kernel(
    const float* __restrict__ H, int n, float* __restrict__ gsum, float* __restrict__ gsq)
{
    int tid = threadIdx.x;
    int col = tid & 127;
    float s = 0.f, s2 = 0.f;
    for (int row = blockIdx.x * 2 + (tid >> 7); row < n; row += gridDim.x * 2) {
        float v = H[(size_t)row * D + col];
        s += v;
        s2 += v * v;
    }
    __shared__ float sh[256], sh2[256];
    sh[tid] = s;
    sh2[tid] = s2;
    __syncthreads();
    if (tid < 128) {
        atomicAdd(&gsum[col], sh[tid] + sh[tid + 128]);
        atomicAdd(&gsq[col], sh2[tid] + sh2[tid + 128]);
    }
}

__global__ void bn_finalize_kernel(const float* __restrict__ gsum, const float* __restrict__ gsq,
                                   const float* __restrict__ gamma, const float* __restrict__ beta,
                                   float n, float* __restrict__ scale, float* __restrict__ shift)
{
    int c = threadIdx.x;  // 128
    float mu = gsum[c] / n;
    float var = gsq[c] / n - mu * mu;
    float sc = gamma[c] * rsqrtf(var + BN_EPS);
    scale[c] = sc;
    shift[c] = beta[c] - mu * sc;
}

// ---------------- pooling (fused bn2+relu) ----------------
__global__ __launch_bounds__(128) void pool_kernel(
    const float* __restrict__ H, const float* __restrict__ scale, const float* __restrict__ shift,
    const int* __restrict__ gstart, const int* __restrict__ gcnt, float* __restrict__ pooled)
{
    int g = blockIdx.x;
    int tid = threadIdx.x;  // 128
    int s = gstart[g], c = gcnt[g];
    float sc = scale[tid], sh = shift[tid];
    float a = 0.f;
    for (int i = 0; i < c; ++i) {
        float v = H[(size_t)(s + i) * D + tid];
        a += fmaxf(v * sc + sh, 0.f);
    }
    int cm = c > 1 ? c : 1;
    pooled[(size_t)g * D + tid] = a / (float)cm;
}

// ---------------- classifier + log_softmax ----------------
__global__ __launch_bounds__(64) void classify_kernel(
    const float* __restrict__ pooled, const float* __restrict__ fcw,
    const float* __restrict__ fcb, float* __restrict__ out)
{
    int g = blockIdx.x;
    int tid = threadIdx.x;  // 64
    __shared__ float prow[D];
    __shared__ float lg[C_CLASSES];
    prow[tid] = pooled[(size_t)g * D + tid];
    prow[tid + 64] = pooled[(size_t)g * D + 64 + tid];
    __syncthreads();
    if (tid < C_CLASSES) {
        float s = fcb[tid];
        for (int d = 0; d < D; ++d) s += prow[d] * fcw[d * C_CLASSES + tid];
        lg[tid] = s;
    }
    __syncthreads();
    if (tid == 0) {
        float m = -1e30f;
        for (int c = 0; c < C_CLASSES; ++c) m = fmaxf(m, lg[c]);
        float se = 0.f;
        for (int c = 0; c < C_CLASSES; ++c) se += expf(lg[c] - m);
        float lse = m + logf(se);
        for (int c = 0; c < C_CLASSES; ++c) out[(size_t)g * C_CLASSES + c] = lg[c] - lse;
    }
}

extern "C" void kernel_launch(void* const* d_in, const int* in_sizes, int n_in,
                              void* d_out, int out_size, void* d_ws, size_t ws_size,
                              hipStream_t stream) {
    const float* x   = (const float*)d_in[0];
    const int* ei    = (const int*)d_in[1];
    const int* batch = (const int*)d_in[2];
    const float* w1  = (const float*)d_in[3];
    const float* b1  = (const float*)d_in[4];
    const float* w2  = (const float*)d_in[5];
    const float* b2  = (const float*)d_in[6];
    const float* w3  = (const float*)d_in[7];
    const float* b3  = (const float*)d_in[8];
    const float* g1  = (const float*)d_in[9];
    const float* be1 = (const float*)d_in[10];
    const float* g2  = (const float*)d_in[11];
    const float* be2 = (const float*)d_in[12];
    const float* fcw = (const float*)d_in[13];
    const float* fcb = (const float*)d_in[14];

    const int N = in_sizes[0] / D;
    const int E = in_sizes[1] / 2;
    const int* src = ei;
    const int* dst = ei + E;
    const int nbuck = (N + 255) >> 8;

    char* p = (char*)d_ws;
    auto alloc = [&](size_t bytes) -> void* {
        void* r = (void*)p;
        p += (bytes + 255) & ~(size_t)255;
        return r;
    };
    float* dinv     = (float*)alloc((size_t)N * 4);
    int*   rowPtr   = (int*)alloc((size_t)(N + 1) * 4);
    int*   colIdx   = (int*)alloc((size_t)E * 4);
    uint2* pairs    = (uint2*)alloc((size_t)E * 8);
    int*   bucketCnt    = (int*)alloc(NBUCK_MAX * 4);
    int*   bucketBase   = (int*)alloc((NBUCK_MAX + 1) * 4);
    int*   bucketCursor = (int*)alloc(NBUCK_MAX * 4);
    int*   gcnt    = (int*)alloc(G_GRAPHS * 4);
    int*   gstart  = (int*)alloc(G_GRAPHS * 4);
    float* statsacc= (float*)alloc(4 * D * 4);
    float* gsum1 = statsacc, *gsq1 = statsacc + D, *gsum2 = statsacc + 2 * D, *gsq2 = statsacc + 3 * D;
    float* sc1     = (float*)alloc(D * 4);
    float* sh1     = (float*)alloc(D * 4);
    float* sc2     = (float*)alloc(D * 4);
    float* sh2     = (float*)alloc(D * 4);
    float* pooled  = (float*)alloc((size_t)G_GRAPHS * D * 4);
    unsigned short* tmp = (unsigned short*)alloc((size_t)N * D * 2);  // bf16
    float* hbuf    = (float*)alloc((size_t)N * D * 4);

    hipMemsetAsync(bucketCnt, 0, NBUCK_MAX * 4, stream);
    hipMemsetAsync(gcnt, 0, G_GRAPHS * 4, stream);
    hipMemsetAsync(statsacc, 0, 4 * D * 4, stream);

    // ---- graph structure ----
    bucket_hist_kernel<<<512, 256, 0, stream>>>(dst, bucketCnt, E, nbuck);
    scan_buckets_kernel<<<1, 512, 0, stream>>>(bucketCnt, bucketBase, bucketCursor, rowPtr, nbuck, N, E);
    scatter_pairs_kernel<<<(E + EDGE_CHUNK - 1) / EDGE_CHUNK, 256, 0, stream>>>(src, dst, bucketCursor, pairs, E);
    bucket_sort_kernel<<<nbuck, 256, 0, stream>>>(pairs, bucketBase, colIdx, rowPtr, dinv, N);
    graph_count_kernel<<<(N + 255) / 256, 256, 0, stream>>>(batch, gcnt, N);
    scan_graphs_kernel<<<1, 512, 0, stream>>>(gcnt, gstart);

    const int GB = (N + GEMM_ROWS - 1) / GEMM_ROWS;
    const int AB = (N + 3) / 4;

    gemm128_kernel<<<GB, 256, 0, stream>>>(x, w1, nullptr, nullptr, tmp, N);
    aggregate_kernel<<<AB, 256, 0, stream>>>((const uint4*)tmp, colIdx, rowPtr, dinv, b1, hbuf, N);
    gemm128_kernel<<<GB, 256, 0, stream>>>(hbuf, w2, nullptr, nullptr, tmp, N);
    aggregate_kernel<<<AB, 256, 0, stream>>>((const uint4*)tmp, colIdx, rowPtr, dinv, b2, hbuf, N);
    bn_stats_kernel<<<512, 256, 0, stream>>>(hbuf, N, gsum1, gsq1);
    bn_finalize_kernel<<<1, 128, 0, stream>>>(gsum1, gsq1, g1, be1, (float)N, sc1, sh1);
    gemm128_kernel<<<GB, 256, 0, stream>>>(hbuf, w3, sc1, sh1, tmp, N);
    aggregate_kernel<<<AB, 256, 0, stream>>>((const uint4*)tmp, colIdx, rowPtr, dinv, b3, hbuf, N);
    bn_stats_kernel<<<512, 256, 0, stream>>>(hbuf, N, gsum2, gsq2);
    bn_finalize_kernel<<<1, 128, 0, stream>>>(gsum2, gsq2, g2, be2, (float)N, sc2, sh2);
    pool_kernel<<<G_GRAPHS, 128, 0, stream>>>(hbuf, sc2, sh2, gstart, gcnt, pooled);
    classify_kernel<<<G_GRAPHS, 64, 0, stream>>>(pooled, fcw, fcb, (float*)d_out);
}

// Round 5
// 682.581 us; speedup vs baseline: 1.7334x; 1.2438x over previous
//
#include <hip/hip_runtime.h>
#include <hip/hip_bf16.h>
#include <math.h>

#define D 128
#define G_GRAPHS 512
#define C_CLASSES 10
#define BN_EPS 1e-5f
#define NBUCK_MAX 512     // supports N <= 131072 (bucket = node >> 8)
#define EDGE_CHUNK 4096
#define EPT 16            // EDGE_CHUNK / 256

typedef unsigned short u16;
typedef unsigned short ushort4_t __attribute__((ext_vector_type(4)));
typedef unsigned short ushort8_t __attribute__((ext_vector_type(8)));
typedef __bf16 bf16x8 __attribute__((ext_vector_type(8)));
typedef float floatx4 __attribute__((ext_vector_type(4)));
union B8 { ushort8_t u; bf16x8 b; };

__device__ __forceinline__ float bf_lo(unsigned int v) { return __uint_as_float(v << 16); }
__device__ __forceinline__ float bf_hi(unsigned int v) { return __uint_as_float(v & 0xffff0000u); }
__device__ __forceinline__ u16 f2bf(float f) {
    union { float f; unsigned int u; } x; x.f = f;
    unsigned int r = x.u + 0x7fff + ((x.u >> 16) & 1);  // RN-even
    return (u16)(r >> 16);
}

// ============ CSR build: two-level counting sort ============

__global__ __launch_bounds__(256) void bucket_hist_kernel(
    const int* __restrict__ dst, int* __restrict__ bucketCnt, int E, int nbuck)
{
    __shared__ int h[NBUCK_MAX];
    int tid = threadIdx.x;
    for (int i = tid; i < NBUCK_MAX; i += 256) h[i] = 0;
    __syncthreads();
    for (int i = blockIdx.x * 256 + tid; i < E; i += gridDim.x * 256)
        atomicAdd(&h[dst[i] >> 8], 1);
    __syncthreads();
    for (int i = tid; i < nbuck; i += 256)
        if (h[i]) atomicAdd(&bucketCnt[i], h[i]);
}

__global__ void scan_buckets_kernel(
    const int* __restrict__ bucketCnt, int* __restrict__ bucketBase,
    int* __restrict__ bucketCursor, int* __restrict__ rowPtr, int nbuck, int N, int E)
{
    __shared__ int buf[2][512];
    int tid = threadIdx.x;
    int v = (tid < nbuck) ? bucketCnt[tid] : 0;
    buf[0][tid] = v;
    __syncthreads();
    int cur = 0;
    for (int off = 1; off < 512; off <<= 1) {
        buf[1 - cur][tid] = buf[cur][tid] + ((tid >= off) ? buf[cur][tid - off] : 0);
        cur ^= 1;
        __syncthreads();
    }
    if (tid < nbuck) {
        int b = buf[cur][tid] - v;  // exclusive
        bucketBase[tid] = b;
        bucketCursor[tid] = b;
    }
    if (tid == 0) { bucketBase[nbuck] = E; rowPtr[N] = E; }
}

__global__ __launch_bounds__(256) void scatter_pairs_kernel(
    const int* __restrict__ src, const int* __restrict__ dst,
    int* __restrict__ bucketCursor, uint2* __restrict__ pairs, int E)
{
    __shared__ int h[NBUCK_MAX];
    __shared__ int base[NBUCK_MAX];
    int tid = threadIdx.x;
    int e0 = blockIdx.x * EDGE_CHUNK;
    for (int i = tid; i < NBUCK_MAX; i += 256) h[i] = 0;
    __syncthreads();
    int s[EPT], d[EPT], r[EPT];
#pragma unroll
    for (int j = 0; j < EPT; ++j) {
        int i = e0 + j * 256 + tid;
        if (i < E) {
            s[j] = src[i];
            d[j] = dst[i];
            r[j] = atomicAdd(&h[d[j] >> 8], 1);
        } else {
            d[j] = -1;
        }
    }
    __syncthreads();
    for (int i = tid; i < NBUCK_MAX; i += 256)
        if (h[i]) base[i] = atomicAdd(&bucketCursor[i], h[i]);
    __syncthreads();
#pragma unroll
    for (int j = 0; j < EPT; ++j) {
        if (d[j] >= 0) {
            int b = d[j] >> 8;
            pairs[base[b] + r[j]] = make_uint2((unsigned)s[j], (unsigned)d[j]);
        }
    }
}

__global__ __launch_bounds__(256) void bucket_sort_kernel(
    const uint2* __restrict__ pairs, const int* __restrict__ bucketBase,
    int* __restrict__ colIdx, int* __restrict__ rowPtr, float* __restrict__ dinv, int N)
{
    __shared__ int h[256];
    __shared__ int cur[256];
    __shared__ int sbuf[2][256];
    int tid = threadIdx.x;
    int b = blockIdx.x;
    int s = bucketBase[b], e = bucketBase[b + 1];
    h[tid] = 0;
    __syncthreads();
    for (int i = s + tid; i < e; i += 256)
        atomicAdd(&h[pairs[i].y & 255], 1);
    __syncthreads();
    int cnt = h[tid];
    sbuf[0][tid] = cnt;
    __syncthreads();
    int c = 0;
    for (int off = 1; off < 256; off <<= 1) {
        sbuf[1 - c][tid] = sbuf[c][tid] + ((tid >= off) ? sbuf[c][tid - off] : 0);
        c ^= 1;
        __syncthreads();
    }
    int excl = sbuf[c][tid] - cnt;
    int v = b * 256 + tid;
    if (v < N) {
        rowPtr[v] = s + excl;
        dinv[v] = rsqrtf((float)(cnt + 1));  // +1 self loop
    }
    cur[tid] = s + excl;
    __syncthreads();
    for (int i = s + tid; i < e; i += 256) {
        uint2 p = pairs[i];
        int pos = atomicAdd(&cur[p.y & 255], 1);
        colIdx[pos] = (int)p.x;
    }
}

// ---------------- graph segments ----------------
__global__ void graph_count_kernel(const int* __restrict__ batch, int* __restrict__ gcnt, int n) {
    int i = blockIdx.x * blockDim.x + threadIdx.x;
    if (i < n) atomicAdd(&gcnt[batch[i]], 1);
}

__global__ void scan_graphs_kernel(const int* __restrict__ cnt, int* __restrict__ start) {
    __shared__ int buf[2][512];
    int tid = threadIdx.x;  // exactly 512 threads
    int v = cnt[tid];
    buf[0][tid] = v;
    __syncthreads();
    int cur = 0;
    for (int off = 1; off < 512; off <<= 1) {
        buf[1 - cur][tid] = buf[cur][tid] + ((tid >= off) ? buf[cur][tid - off] : 0);
        cur ^= 1;
        __syncthreads();
    }
    start[tid] = buf[cur][tid] - v;
}

// ---------------- W pre-transpose+convert: Wt[n][k] bf16, one block per weight ----------------
__global__ __launch_bounds__(256) void wconv_kernel(
    const float4* __restrict__ w1, const float4* __restrict__ w2,
    const float4* __restrict__ w3, u16* __restrict__ wtAll)
{
    const float4* W = (blockIdx.x == 0) ? w1 : (blockIdx.x == 1) ? w2 : w3;
    u16* Wt = wtAll + (size_t)blockIdx.x * D * D;
    int tid = threadIdx.x;
#pragma unroll
    for (int i = 0; i < 16; ++i) {
        int idx = tid + i * 256;        // = k*32 + c4
        int k = idx >> 5, c4 = idx & 31;
        float4 v = W[idx];
        Wt[(4 * c4 + 0) * D + k] = f2bf(v.x);
        Wt[(4 * c4 + 1) * D + k] = f2bf(v.y);
        Wt[(4 * c4 + 2) * D + k] = f2bf(v.z);
        Wt[(4 * c4 + 3) * D + k] = f2bf(v.w);
    }
}

// ---------------- MFMA GEMM: Y(bf16) = act(X fp32) @ W, 64 rows/block ----------------
// LDS stride 136 ushorts keeps ds_read_b128 uniform across banks; 52 KB -> 3 blocks/CU.
#define XS_STRIDE 136
__global__ __launch_bounds__(256) void gemm_mfma_kernel(
    const float4* __restrict__ X, const u16* __restrict__ Wt,
    const float* __restrict__ scale, const float* __restrict__ shift,
    u16* __restrict__ Y, int nrows)
{
    __shared__ __align__(16) u16 Xs[64 * XS_STRIDE];
    __shared__ __align__(16) u16 Ws[128 * XS_STRIDE];
    int tid = threadIdx.x;
    int row0 = blockIdx.x * 64;
    bool fuse = (scale != nullptr);

    // stage Wt (bf16 packed [n][k]) -> LDS with padded stride
    const ushort8_t* Wv = (const ushort8_t*)Wt;
#pragma unroll
    for (int i = 0; i < 8; ++i) {
        int idx = tid + i * 256;        // = n*16 + c8
        int n = idx >> 4, c8 = idx & 15;
        *(ushort8_t*)&Ws[n * XS_STRIDE + c8 * 8] = Wv[idx];
    }
    // stage X fp32 -> bf16 (optional fused bn+relu)
#pragma unroll
    for (int i = 0; i < 8; ++i) {
        int idx = tid + i * 256;        // = r*32 + c4
        int r = idx >> 5, c4 = idx & 31;
        int gr = row0 + r;
        float4 v = make_float4(0.f, 0.f, 0.f, 0.f);
        if (gr < nrows) v = X[(size_t)gr * 32 + c4];
        if (fuse) {
            int k = c4 * 4;
            v.x = fmaxf(v.x * scale[k] + shift[k], 0.f);
            v.y = fmaxf(v.y * scale[k + 1] + shift[k + 1], 0.f);
            v.z = fmaxf(v.z * scale[k + 2] + shift[k + 2], 0.f);
            v.w = fmaxf(v.w * scale[k + 3] + shift[k + 3], 0.f);
        }
        ushort4_t o;
        o.x = f2bf(v.x); o.y = f2bf(v.y); o.z = f2bf(v.z); o.w = f2bf(v.w);
        *(ushort4_t*)&Xs[r * XS_STRIDE + c4 * 4] = o;
    }
    __syncthreads();

    int wid = tid >> 6, lane = tid & 63;
    int m = lane & 15, quad = lane >> 4;
    int arow = wid * 16 + m;

    floatx4 acc[8] = {};
#pragma unroll
    for (int ks = 0; ks < 4; ++ks) {
        int kk = ks * 32 + quad * 8;
        B8 a;
        a.u = *(const ushort8_t*)&Xs[arow * XS_STRIDE + kk];
#pragma unroll
        for (int t = 0; t < 8; ++t) {
            B8 b;
            b.u = *(const ushort8_t*)&Ws[(t * 16 + m) * XS_STRIDE + kk];
            acc[t] = __builtin_amdgcn_mfma_f32_16x16x32_bf16(a.b, b.b, acc[t], 0, 0, 0);
        }
    }

    // epilogue: D col=lane&15, row=quad*4+reg
#pragma unroll
    for (int t = 0; t < 8; ++t) {
#pragma unroll
        for (int r = 0; r < 4; ++r) {
            int grow = row0 + wid * 16 + quad * 4 + r;
            if (grow < nrows) Y[(size_t)grow * D + t * 16 + m] = f2bf(acc[t][r]);
        }
    }
}

// ---------------- aggregation v2: 4 edges/iter, dwordx4 gathers ----------------
__global__ __launch_bounds__(256) void aggregate_kernel(
    const uint4* __restrict__ T, const int* __restrict__ colIdx,
    const int* __restrict__ rowPtr, const float* __restrict__ dinv,
    const float* __restrict__ bias, float* __restrict__ outH, int n)
{
    int wid = threadIdx.x >> 6;
    int lane = threadIdx.x & 63;
    int row = blockIdx.x * 4 + wid;
    if (row >= n) return;
    int fg = lane & 15;
    int eg = lane >> 4;

    float dr = dinv[row];
    float acc[8] = {};

    if (eg == 0) {
        uint4 sv = T[(size_t)row * 16 + fg];
        acc[0] = dr * bf_lo(sv.x); acc[1] = dr * bf_hi(sv.x);
        acc[2] = dr * bf_lo(sv.y); acc[3] = dr * bf_hi(sv.y);
        acc[4] = dr * bf_lo(sv.z); acc[5] = dr * bf_hi(sv.z);
        acc[6] = dr * bf_lo(sv.w); acc[7] = dr * bf_hi(sv.w);
    }

    int s = rowPtr[row], e = rowPtr[row + 1];
    for (int j0 = s; j0 < e; j0 += 64) {
        int m = e - j0;
        if (m > 64) m = 64;
        int u = row;
        float du = 0.f;
        if (lane < m) {
            u = colIdx[j0 + lane];
            du = dinv[u];
        }
        int nt = (m + 3) >> 2;
        for (int t = 0; t < nt; ++t) {
            int idx = t * 4 + eg;
            int uu = __shfl(u, idx);
            float duu = __shfl(du, idx);
            uint4 tw = T[(size_t)uu * 16 + fg];
            acc[0] += duu * bf_lo(tw.x); acc[1] += duu * bf_hi(tw.x);
            acc[2] += duu * bf_lo(tw.y); acc[3] += duu * bf_hi(tw.y);
            acc[4] += duu * bf_lo(tw.z); acc[5] += duu * bf_hi(tw.z);
            acc[6] += duu * bf_lo(tw.w); acc[7] += duu * bf_hi(tw.w);
        }
    }

#pragma unroll
    for (int off = 16; off < 64; off <<= 1) {
#pragma unroll
        for (int i = 0; i < 8; ++i) acc[i] += __shfl_xor(acc[i], off);
    }

    const float2* bp = (const float2*)bias;
    int pidx = fg * 4 + eg;
    float2 b = bp[pidx];
    float2 o;
    o.x = fmaxf(dr * acc[eg * 2] + b.x, 0.f);
    o.y = fmaxf(dr * acc[eg * 2 + 1] + b.y, 0.f);
    ((float2*)outH)[(size_t)row * 64 + pidx] = o;
}

// ---------------- batchnorm stats ----------------
__global__ __launch_bounds__(256) void bn_stats_kernel(
    const float* __restrict__ H, int n, float* __restrict__ gsum, float* __restrict__ gsq)
{
    int tid = threadIdx.x;
    int col = tid & 127;
    float s = 0.f, s2 = 0.f;
    for (int row = blockIdx.x * 2 + (tid >> 7); row < n; row += gridDim.x * 2) {
        float v = H[(size_t)row * D + col];
        s += v;
        s2 += v * v;
    }
    __shared__ float sh[256], sh2[256];
    sh[tid] = s;
    sh2[tid] = s2;
    __syncthreads();
    if (tid < 128) {
        atomicAdd(&gsum[col], sh[tid] + sh[tid + 128]);
        atomicAdd(&gsq[col], sh2[tid] + sh2[tid + 128]);
    }
}

__global__ void bn_finalize_kernel(const float* __restrict__ gsum, const float* __restrict__ gsq,
                                   const float* __restrict__ gamma, const float* __restrict__ beta,
                                   float n, float* __restrict__ scale, float* __restrict__ shift)
{
    int c = threadIdx.x;  // 128
    float mu = gsum[c] / n;
    float var = gsq[c] / n - mu * mu;
    float sc = gamma[c] * rsqrtf(var + BN_EPS);
    scale[c] = sc;
    shift[c] = beta[c] - mu * sc;
}

// ---------------- pooling (fused bn2+relu) ----------------
__global__ __launch_bounds__(128) void pool_kernel(
    const float* __restrict__ H, const float* __restrict__ scale, const float* __restrict__ shift,
    const int* __restrict__ gstart, const int* __restrict__ gcnt, float* __restrict__ pooled)
{
    int g = blockIdx.x;
    int tid = threadIdx.x;  // 128
    int s = gstart[g], c = gcnt[g];
    float sc = scale[tid], sh = shift[tid];
    float a = 0.f;
    for (int i = 0; i < c; ++i) {
        float v = H[(size_t)(s + i) * D + tid];
        a += fmaxf(v * sc + sh, 0.f);
    }
    int cm = c > 1 ? c : 1;
    pooled[(size_t)g * D + tid] = a / (float)cm;
}

// ---------------- classifier + log_softmax ----------------
__global__ __launch_bounds__(64) void classify_kernel(
    const float* __restrict__ pooled, const float* __restrict__ fcw,
    const float* __restrict__ fcb, float* __restrict__ out)
{
    int g = blockIdx.x;
    int tid = threadIdx.x;  // 64
    __shared__ float prow[D];
    __shared__ float lg[C_CLASSES];
    prow[tid] = pooled[(size_t)g * D + tid];
    prow[tid + 64] = pooled[(size_t)g * D + 64 + tid];
    __syncthreads();
    if (tid < C_CLASSES) {
        float s = fcb[tid];
        for (int d = 0; d < D; ++d) s += prow[d] * fcw[d * C_CLASSES + tid];
        lg[tid] = s;
    }
    __syncthreads();
    if (tid == 0) {
        float m = -1e30f;
        for (int c = 0; c < C_CLASSES; ++c) m = fmaxf(m, lg[c]);
        float se = 0.f;
        for (int c = 0; c < C_CLASSES; ++c) se += expf(lg[c] - m);
        float lse = m + logf(se);
        for (int c = 0; c < C_CLASSES; ++c) out[(size_t)g * C_CLASSES + c] = lg[c] - lse;
    }
}

extern "C" void kernel_launch(void* const* d_in, const int* in_sizes, int n_in,
                              void* d_out, int out_size, void* d_ws, size_t ws_size,
                              hipStream_t stream) {
    const float* x   = (const float*)d_in[0];
    const int* ei    = (const int*)d_in[1];
    const int* batch = (const int*)d_in[2];
    const float* w1  = (const float*)d_in[3];
    const float* b1  = (const float*)d_in[4];
    const float* w2  = (const float*)d_in[5];
    const float* b2  = (const float*)d_in[6];
    const float* w3  = (const float*)d_in[7];
    const float* b3  = (const float*)d_in[8];
    const float* g1  = (const float*)d_in[9];
    const float* be1 = (const float*)d_in[10];
    const float* g2  = (const float*)d_in[11];
    const float* be2 = (const float*)d_in[12];
    const float* fcw = (const float*)d_in[13];
    const float* fcb = (const float*)d_in[14];

    const int N = in_sizes[0] / D;
    const int E = in_sizes[1] / 2;
    const int* src = ei;
    const int* dst = ei + E;
    const int nbuck = (N + 255) >> 8;

    char* p = (char*)d_ws;
    auto alloc = [&](size_t bytes) -> void* {
        void* r = (void*)p;
        p += (bytes + 255) & ~(size_t)255;
        return r;
    };
    float* dinv     = (float*)alloc((size_t)N * 4);
    int*   rowPtr   = (int*)alloc((size_t)(N + 1) * 4);
    int*   colIdx   = (int*)alloc((size_t)E * 4);
    uint2* pairs    = (uint2*)alloc((size_t)E * 8);
    int*   bucketCnt    = (int*)alloc(NBUCK_MAX * 4);
    int*   bucketBase   = (int*)alloc((NBUCK_MAX + 1) * 4);
    int*   bucketCursor = (int*)alloc(NBUCK_MAX * 4);
    int*   gcnt    = (int*)alloc(G_GRAPHS * 4);
    int*   gstart  = (int*)alloc(G_GRAPHS * 4);
    float* statsacc= (float*)alloc(4 * D * 4);
    float* gsum1 = statsacc, *gsq1 = statsacc + D, *gsum2 = statsacc + 2 * D, *gsq2 = statsacc + 3 * D;
    float* sc1     = (float*)alloc(D * 4);
    float* sh1     = (float*)alloc(D * 4);
    float* sc2     = (float*)alloc(D * 4);
    float* sh2     = (float*)alloc(D * 4);
    float* pooled  = (float*)alloc((size_t)G_GRAPHS * D * 4);
    u16*   wtAll   = (u16*)alloc((size_t)3 * D * D * 2);   // bf16 W^T x3
    u16*   tmp     = (u16*)alloc((size_t)N * D * 2);       // bf16
    float* hbuf    = (float*)alloc((size_t)N * D * 4);

    hipMemsetAsync(bucketCnt, 0, NBUCK_MAX * 4, stream);
    hipMemsetAsync(gcnt, 0, G_GRAPHS * 4, stream);
    hipMemsetAsync(statsacc, 0, 4 * D * 4, stream);

    // ---- graph structure ----
    bucket_hist_kernel<<<512, 256, 0, stream>>>(dst, bucketCnt, E, nbuck);
    scan_buckets_kernel<<<1, 512, 0, stream>>>(bucketCnt, bucketBase, bucketCursor, rowPtr, nbuck, N, E);
    scatter_pairs_kernel<<<(E + EDGE_CHUNK - 1) / EDGE_CHUNK, 256, 0, stream>>>(src, dst, bucketCursor, pairs, E);
    bucket_sort_kernel<<<nbuck, 256, 0, stream>>>(pairs, bucketBase, colIdx, rowPtr, dinv, N);
    graph_count_kernel<<<(N + 255) / 256, 256, 0, stream>>>(batch, gcnt, N);
    scan_graphs_kernel<<<1, 512, 0, stream>>>(gcnt, gstart);
    wconv_kernel<<<3, 256, 0, stream>>>((const float4*)w1, (const float4*)w2, (const float4*)w3, wtAll);

    const int GB = (N + 63) / 64;
    const int AB = (N + 3) / 4;

    gemm_mfma_kernel<<<GB, 256, 0, stream>>>((const float4*)x, wtAll, nullptr, nullptr, tmp, N);
    aggregate_kernel<<<AB, 256, 0, stream>>>((const uint4*)tmp, colIdx, rowPtr, dinv, b1, hbuf, N);
    gemm_mfma_kernel<<<GB, 256, 0, stream>>>((const float4*)hbuf, wtAll + D * D, nullptr, nullptr, tmp, N);
    aggregate_kernel<<<AB, 256, 0, stream>>>((const uint4*)tmp, colIdx, rowPtr, dinv, b2, hbuf, N);
    bn_stats_kernel<<<512, 256, 0, stream>>>(hbuf, N, gsum1, gsq1);
    bn_finalize_kernel<<<1, 128, 0, stream>>>(gsum1, gsq1, g1, be1, (float)N, sc1, sh1);
    gemm_mfma_kernel<<<GB, 256, 0, stream>>>((const float4*)hbuf, wtAll + 2 * D * D, sc1, sh1, tmp, N);
    aggregate_kernel<<<AB, 256, 0, stream>>>((const uint4*)tmp, colIdx, rowPtr, dinv, b3, hbuf, N);
    bn_stats_kernel<<<512, 256, 0, stream>>>(hbuf, N, gsum2, gsq2);
    bn_finalize_kernel<<<1, 128, 0, stream>>>(gsum2, gsq2, g2, be2, (float)N, sc2, sh2);
    pool_kernel<<<G_GRAPHS, 128, 0, stream>>>(hbuf, sc2, sh2, gstart, gcnt, pooled);
    classify_kernel<<<G_GRAPHS, 64, 0, stream>>>(pooled, fcw, fcb, (float*)d_out);
}

// Round 6
// 600.654 us; speedup vs baseline: 1.9698x; 1.1364x over previous
//
#include <hip/hip_runtime.h>
#include <hip/hip_bf16.h>
#include <math.h>

#define D 128
#define G_GRAPHS 512
#define C_CLASSES 10
#define BN_EPS 1e-5f
#define NBUCK_MAX 512     // supports N <= 131072 (bucket = node >> 8)
#define EDGE_CHUNK 4096
#define EPT 16            // EDGE_CHUNK / 256

typedef unsigned short u16;
typedef unsigned short ushort4_t __attribute__((ext_vector_type(4)));
typedef unsigned short ushort8_t __attribute__((ext_vector_type(8)));
typedef __bf16 bf16x8 __attribute__((ext_vector_type(8)));
typedef float floatx4 __attribute__((ext_vector_type(4)));
union B8 { ushort8_t u; bf16x8 b; };

__device__ __forceinline__ float bf_lo(unsigned int v) { return __uint_as_float(v << 16); }
__device__ __forceinline__ float bf_hi(unsigned int v) { return __uint_as_float(v & 0xffff0000u); }
__device__ __forceinline__ u16 f2bf(float f) {
    union { float f; unsigned int u; } x; x.f = f;
    unsigned int r = x.u + 0x7fff + ((x.u >> 16) & 1);  // RN-even
    return (u16)(r >> 16);
}

// ============ CSR build: two-level counting sort ============

__global__ __launch_bounds__(256) void bucket_hist_kernel(
    const int* __restrict__ dst, int* __restrict__ bucketCnt, int E, int nbuck)
{
    __shared__ int h[NBUCK_MAX];
    int tid = threadIdx.x;
    for (int i = tid; i < NBUCK_MAX; i += 256) h[i] = 0;
    __syncthreads();
    for (int i = blockIdx.x * 256 + tid; i < E; i += gridDim.x * 256)
        atomicAdd(&h[dst[i] >> 8], 1);
    __syncthreads();
    for (int i = tid; i < nbuck; i += 256)
        if (h[i]) atomicAdd(&bucketCnt[i], h[i]);
}

__global__ void scan_buckets_kernel(
    const int* __restrict__ bucketCnt, int* __restrict__ bucketBase,
    int* __restrict__ bucketCursor, int* __restrict__ rowPtr, int nbuck, int N, int E)
{
    __shared__ int buf[2][512];
    int tid = threadIdx.x;
    int v = (tid < nbuck) ? bucketCnt[tid] : 0;
    buf[0][tid] = v;
    __syncthreads();
    int cur = 0;
    for (int off = 1; off < 512; off <<= 1) {
        buf[1 - cur][tid] = buf[cur][tid] + ((tid >= off) ? buf[cur][tid - off] : 0);
        cur ^= 1;
        __syncthreads();
    }
    if (tid < nbuck) {
        int b = buf[cur][tid] - v;  // exclusive
        bucketBase[tid] = b;
        bucketCursor[tid] = b;
    }
    if (tid == 0) { bucketBase[nbuck] = E; rowPtr[N] = E; }
}

__global__ __launch_bounds__(256) void scatter_pairs_kernel(
    const int* __restrict__ src, const int* __restrict__ dst,
    int* __restrict__ bucketCursor, uint2* __restrict__ pairs, int E)
{
    __shared__ int h[NBUCK_MAX];
    __shared__ int base[NBUCK_MAX];
    int tid = threadIdx.x;
    int e0 = blockIdx.x * EDGE_CHUNK;
    for (int i = tid; i < NBUCK_MAX; i += 256) h[i] = 0;
    __syncthreads();
    int s[EPT], d[EPT], r[EPT];
#pragma unroll
    for (int j = 0; j < EPT; ++j) {
        int i = e0 + j * 256 + tid;
        if (i < E) {
            s[j] = src[i];
            d[j] = dst[i];
            r[j] = atomicAdd(&h[d[j] >> 8], 1);
        } else {
            d[j] = -1;
        }
    }
    __syncthreads();
    for (int i = tid; i < NBUCK_MAX; i += 256)
        if (h[i]) base[i] = atomicAdd(&bucketCursor[i], h[i]);
    __syncthreads();
#pragma unroll
    for (int j = 0; j < EPT; ++j) {
        if (d[j] >= 0) {
            int b = d[j] >> 8;
            pairs[base[b] + r[j]] = make_uint2((unsigned)s[j], (unsigned)d[j]);
        }
    }
}

__global__ __launch_bounds__(256) void bucket_sort_kernel(
    const uint2* __restrict__ pairs, const int* __restrict__ bucketBase,
    int* __restrict__ colIdx, int* __restrict__ rowPtr, float* __restrict__ dinv, int N)
{
    __shared__ int h[256];
    __shared__ int cur[256];
    __shared__ int sbuf[2][256];
    int tid = threadIdx.x;
    int b = blockIdx.x;
    int s = bucketBase[b], e = bucketBase[b + 1];
    h[tid] = 0;
    __syncthreads();
    for (int i = s + tid; i < e; i += 256)
        atomicAdd(&h[pairs[i].y & 255], 1);
    __syncthreads();
    int cnt = h[tid];
    sbuf[0][tid] = cnt;
    __syncthreads();
    int c = 0;
    for (int off = 1; off < 256; off <<= 1) {
        sbuf[1 - c][tid] = sbuf[c][tid] + ((tid >= off) ? sbuf[c][tid - off] : 0);
        c ^= 1;
        __syncthreads();
    }
    int excl = sbuf[c][tid] - cnt;
    int v = b * 256 + tid;
    if (v < N) {
        rowPtr[v] = s + excl;
        dinv[v] = rsqrtf((float)(cnt + 1));  // +1 self loop
    }
    cur[tid] = s + excl;
    __syncthreads();
    for (int i = s + tid; i < e; i += 256) {
        uint2 p = pairs[i];
        int pos = atomicAdd(&cur[p.y & 255], 1);
        colIdx[pos] = (int)p.x;
    }
}

// ---------------- graph segments: boundary detection on sorted batch ----------------
__global__ __launch_bounds__(256) void graph_bounds_kernel(
    const int* __restrict__ batch, int* __restrict__ gstart, int N)
{
    int i = blockIdx.x * 256 + threadIdx.x;
    if (i >= N) return;
    int b = batch[i];
    int prev = (i == 0) ? -1 : batch[i - 1];
    if (b != prev) {
        for (int g = prev + 1; g <= b; ++g) gstart[g] = i;  // covers empty graphs
    }
    if (i == N - 1) {
        for (int g = b + 1; g <= G_GRAPHS; ++g) gstart[g] = N;
    }
}

// ---------------- W pre-transpose+convert: Wt[n][k] bf16, one block per weight ----------------
__global__ __launch_bounds__(256) void wconv_kernel(
    const float4* __restrict__ w1, const float4* __restrict__ w2,
    const float4* __restrict__ w3, u16* __restrict__ wtAll)
{
    const float4* W = (blockIdx.x == 0) ? w1 : (blockIdx.x == 1) ? w2 : w3;
    u16* Wt = wtAll + (size_t)blockIdx.x * D * D;
    int tid = threadIdx.x;
#pragma unroll
    for (int i = 0; i < 16; ++i) {
        int idx = tid + i * 256;        // = k*32 + c4
        int k = idx >> 5, c4 = idx & 31;
        float4 v = W[idx];
        Wt[(4 * c4 + 0) * D + k] = f2bf(v.x);
        Wt[(4 * c4 + 1) * D + k] = f2bf(v.y);
        Wt[(4 * c4 + 2) * D + k] = f2bf(v.z);
        Wt[(4 * c4 + 3) * D + k] = f2bf(v.w);
    }
}

// ---------------- MFMA GEMM: Y(bf16) = act(X fp32) @ W, 64 rows/block ----------------
#define XS_STRIDE 136
__global__ __launch_bounds__(256) void gemm_mfma_kernel(
    const float4* __restrict__ X, const u16* __restrict__ Wt,
    const float* __restrict__ scale, const float* __restrict__ shift,
    u16* __restrict__ Y, int nrows)
{
    __shared__ __align__(16) u16 Xs[64 * XS_STRIDE];
    __shared__ __align__(16) u16 Ws[128 * XS_STRIDE];
    int tid = threadIdx.x;
    int row0 = blockIdx.x * 64;
    bool fuse = (scale != nullptr);

    const ushort8_t* Wv = (const ushort8_t*)Wt;
#pragma unroll
    for (int i = 0; i < 8; ++i) {
        int idx = tid + i * 256;        // = n*16 + c8
        int n = idx >> 4, c8 = idx & 15;
        *(ushort8_t*)&Ws[n * XS_STRIDE + c8 * 8] = Wv[idx];
    }
#pragma unroll
    for (int i = 0; i < 8; ++i) {
        int idx = tid + i * 256;        // = r*32 + c4
        int r = idx >> 5, c4 = idx & 31;
        int gr = row0 + r;
        float4 v = make_float4(0.f, 0.f, 0.f, 0.f);
        if (gr < nrows) v = X[(size_t)gr * 32 + c4];
        if (fuse) {
            int k = c4 * 4;
            v.x = fmaxf(v.x * scale[k] + shift[k], 0.f);
            v.y = fmaxf(v.y * scale[k + 1] + shift[k + 1], 0.f);
            v.z = fmaxf(v.z * scale[k + 2] + shift[k + 2], 0.f);
            v.w = fmaxf(v.w * scale[k + 3] + shift[k + 3], 0.f);
        }
        ushort4_t o;
        o.x = f2bf(v.x); o.y = f2bf(v.y); o.z = f2bf(v.z); o.w = f2bf(v.w);
        *(ushort4_t*)&Xs[r * XS_STRIDE + c4 * 4] = o;
    }
    __syncthreads();

    int wid = tid >> 6, lane = tid & 63;
    int m = lane & 15, quad = lane >> 4;
    int arow = wid * 16 + m;

    floatx4 acc[8] = {};
#pragma unroll
    for (int ks = 0; ks < 4; ++ks) {
        int kk = ks * 32 + quad * 8;
        B8 a;
        a.u = *(const ushort8_t*)&Xs[arow * XS_STRIDE + kk];
#pragma unroll
        for (int t = 0; t < 8; ++t) {
            B8 b;
            b.u = *(const ushort8_t*)&Ws[(t * 16 + m) * XS_STRIDE + kk];
            acc[t] = __builtin_amdgcn_mfma_f32_16x16x32_bf16(a.b, b.b, acc[t], 0, 0, 0);
        }
    }

#pragma unroll
    for (int t = 0; t < 8; ++t) {
#pragma unroll
        for (int r = 0; r < 4; ++r) {
            int grow = row0 + wid * 16 + quad * 4 + r;
            if (grow < nrows) Y[(size_t)grow * D + t * 16 + m] = f2bf(acc[t][r]);
        }
    }
}

// ---------------- aggregation v2: 4 edges/iter, dwordx4 gathers ----------------
__global__ __launch_bounds__(256) void aggregate_kernel(
    const uint4* __restrict__ T, const int* __restrict__ colIdx,
    const int* __restrict__ rowPtr, const float* __restrict__ dinv,
    const float* __restrict__ bias, float* __restrict__ outH, int n)
{
    int wid = threadIdx.x >> 6;
    int lane = threadIdx.x & 63;
    int row = blockIdx.x * 4 + wid;
    if (row >= n) return;
    int fg = lane & 15;
    int eg = lane >> 4;

    float dr = dinv[row];
    float acc[8] = {};

    if (eg == 0) {
        uint4 sv = T[(size_t)row * 16 + fg];
        acc[0] = dr * bf_lo(sv.x); acc[1] = dr * bf_hi(sv.x);
        acc[2] = dr * bf_lo(sv.y); acc[3] = dr * bf_hi(sv.y);
        acc[4] = dr * bf_lo(sv.z); acc[5] = dr * bf_hi(sv.z);
        acc[6] = dr * bf_lo(sv.w); acc[7] = dr * bf_hi(sv.w);
    }

    int s = rowPtr[row], e = rowPtr[row + 1];
    for (int j0 = s; j0 < e; j0 += 64) {
        int m = e - j0;
        if (m > 64) m = 64;
        int u = row;
        float du = 0.f;
        if (lane < m) {
            u = colIdx[j0 + lane];
            du = dinv[u];
        }
        int nt = (m + 3) >> 2;
        for (int t = 0; t < nt; ++t) {
            int idx = t * 4 + eg;
            int uu = __shfl(u, idx);
            float duu = __shfl(du, idx);
            uint4 tw = T[(size_t)uu * 16 + fg];
            acc[0] += duu * bf_lo(tw.x); acc[1] += duu * bf_hi(tw.x);
            acc[2] += duu * bf_lo(tw.y); acc[3] += duu * bf_hi(tw.y);
            acc[4] += duu * bf_lo(tw.z); acc[5] += duu * bf_hi(tw.z);
            acc[6] += duu * bf_lo(tw.w); acc[7] += duu * bf_hi(tw.w);
        }
    }

#pragma unroll
    for (int off = 16; off < 64; off <<= 1) {
#pragma unroll
        for (int i = 0; i < 8; ++i) acc[i] += __shfl_xor(acc[i], off);
    }

    const float2* bp = (const float2*)bias;
    int pidx = fg * 4 + eg;
    float2 b = bp[pidx];
    float2 o;
    o.x = fmaxf(dr * acc[eg * 2] + b.x, 0.f);
    o.y = fmaxf(dr * acc[eg * 2 + 1] + b.y, 0.f);
    ((float2*)outH)[(size_t)row * 64 + pidx] = o;
}

// ---------------- batchnorm stats ----------------
__global__ __launch_bounds__(256) void bn_stats_kernel(
    const float* __restrict__ H, int n, float* __restrict__ gsum, float* __restrict__ gsq)
{
    int tid = threadIdx.x;
    int col = tid & 127;
    float s = 0.f, s2 = 0.f;
    for (int row = blockIdx.x * 2 + (tid >> 7); row < n; row += gridDim.x * 2) {
        float v = H[(size_t)row * D + col];
        s += v;
        s2 += v * v;
    }
    __shared__ float sh[256], sh2[256];
    sh[tid] = s;
    sh2[tid] = s2;
    __syncthreads();
    if (tid < 128) {
        atomicAdd(&gsum[col], sh[tid] + sh[tid + 128]);
        atomicAdd(&gsq[col], sh2[tid] + sh2[tid + 128]);
    }
}

__global__ void bn_finalize_kernel(const float* __restrict__ gsum, const float* __restrict__ gsq,
                                   const float* __restrict__ gamma, const float* __restrict__ beta,
                                   float n, float* __restrict__ scale, float* __restrict__ shift)
{
    int c = threadIdx.x;  // 128
    float mu = gsum[c] / n;
    float var = gsq[c] / n - mu * mu;
    float sc = gamma[c] * rsqrtf(var + BN_EPS);
    scale[c] = sc;
    shift[c] = beta[c] - mu * sc;
}

// ---------------- pooling (fused bn2+relu); cnt from gstart diffs ----------------
__global__ __launch_bounds__(128) void pool_kernel(
    const float* __restrict__ H, const float* __restrict__ scale, const float* __restrict__ shift,
    const int* __restrict__ gstart, float* __restrict__ pooled)
{
    int g = blockIdx.x;
    int tid = threadIdx.x;  // 128
    int s = gstart[g], c = gstart[g + 1] - s;
    float sc = scale[tid], sh = shift[tid];
    float a = 0.f;
    for (int i = 0; i < c; ++i) {
        float v = H[(size_t)(s + i) * D + tid];
        a += fmaxf(v * sc + sh, 0.f);
    }
    int cm = c > 1 ? c : 1;
    pooled[(size_t)g * D + tid] = a / (float)cm;
}

// ---------------- classifier + log_softmax ----------------
__global__ __launch_bounds__(64) void classify_kernel(
    const float* __restrict__ pooled, const float* __restrict__ fcw,
    const float* __restrict__ fcb, float* __restrict__ out)
{
    int g = blockIdx.x;
    int tid = threadIdx.x;  // 64
    __shared__ float prow[D];
    __shared__ float lg[C_CLASSES];
    prow[tid] = pooled[(size_t)g * D + tid];
    prow[tid + 64] = pooled[(size_t)g * D + 64 + tid];
    __syncthreads();
    if (tid < C_CLASSES) {
        float s = fcb[tid];
        for (int d = 0; d < D; ++d) s += prow[d] * fcw[d * C_CLASSES + tid];
        lg[tid] = s;
    }
    __syncthreads();
    if (tid == 0) {
        float m = -1e30f;
        for (int c = 0; c < C_CLASSES; ++c) m = fmaxf(m, lg[c]);
        float se = 0.f;
        for (int c = 0; c < C_CLASSES; ++c) se += expf(lg[c] - m);
        float lse = m + logf(se);
        for (int c = 0; c < C_CLASSES; ++c) out[(size_t)g * C_CLASSES + c] = lg[c] - lse;
    }
}

extern "C" void kernel_launch(void* const* d_in, const int* in_sizes, int n_in,
                              void* d_out, int out_size, void* d_ws, size_t ws_size,
                              hipStream_t stream) {
    const float* x   = (const float*)d_in[0];
    const int* ei    = (const int*)d_in[1];
    const int* batch = (const int*)d_in[2];
    const float* w1  = (const float*)d_in[3];
    const float* b1  = (const float*)d_in[4];
    const float* w2  = (const float*)d_in[5];
    const float* b2  = (const float*)d_in[6];
    const float* w3  = (const float*)d_in[7];
    const float* b3  = (const float*)d_in[8];
    const float* g1  = (const float*)d_in[9];
    const float* be1 = (const float*)d_in[10];
    const float* g2  = (const float*)d_in[11];
    const float* be2 = (const float*)d_in[12];
    const float* fcw = (const float*)d_in[13];
    const float* fcb = (const float*)d_in[14];

    const int N = in_sizes[0] / D;
    const int E = in_sizes[1] / 2;
    const int* src = ei;
    const int* dst = ei + E;
    const int nbuck = (N + 255) >> 8;

    char* p = (char*)d_ws;
    auto alloc = [&](size_t bytes) -> void* {
        void* r = (void*)p;
        p += (bytes + 255) & ~(size_t)255;
        return r;
    };
    float* dinv     = (float*)alloc((size_t)N * 4);
    int*   rowPtr   = (int*)alloc((size_t)(N + 1) * 4);
    int*   colIdx   = (int*)alloc((size_t)E * 4);
    uint2* pairs    = (uint2*)alloc((size_t)E * 8);
    int*   bucketCnt    = (int*)alloc(NBUCK_MAX * 4);
    int*   bucketBase   = (int*)alloc((NBUCK_MAX + 1) * 4);
    int*   bucketCursor = (int*)alloc(NBUCK_MAX * 4);
    int*   gstart  = (int*)alloc((G_GRAPHS + 1) * 4);
    float* statsacc= (float*)alloc(4 * D * 4);
    float* gsum1 = statsacc, *gsq1 = statsacc + D, *gsum2 = statsacc + 2 * D, *gsq2 = statsacc + 3 * D;
    float* sc1     = (float*)alloc(D * 4);
    float* sh1     = (float*)alloc(D * 4);
    float* sc2     = (float*)alloc(D * 4);
    float* sh2     = (float*)alloc(D * 4);
    float* pooled  = (float*)alloc((size_t)G_GRAPHS * D * 4);
    u16*   wtAll   = (u16*)alloc((size_t)3 * D * D * 2);   // bf16 W^T x3
    u16*   tmp     = (u16*)alloc((size_t)N * D * 2);       // bf16
    float* hbuf    = (float*)alloc((size_t)N * D * 4);

    hipMemsetAsync(bucketCnt, 0, NBUCK_MAX * 4, stream);
    hipMemsetAsync(statsacc, 0, 4 * D * 4, stream);

    // ---- graph structure ----
    bucket_hist_kernel<<<512, 256, 0, stream>>>(dst, bucketCnt, E, nbuck);
    scan_buckets_kernel<<<1, 512, 0, stream>>>(bucketCnt, bucketBase, bucketCursor, rowPtr, nbuck, N, E);
    scatter_pairs_kernel<<<(E + EDGE_CHUNK - 1) / EDGE_CHUNK, 256, 0, stream>>>(src, dst, bucketCursor, pairs, E);
    bucket_sort_kernel<<<nbuck, 256, 0, stream>>>(pairs, bucketBase, colIdx, rowPtr, dinv, N);
    graph_bounds_kernel<<<(N + 255) / 256, 256, 0, stream>>>(batch, gstart, N);
    wconv_kernel<<<3, 256, 0, stream>>>((const float4*)w1, (const float4*)w2, (const float4*)w3, wtAll);

    const int GB = (N + 63) / 64;
    const int AB = (N + 3) / 4;

    gemm_mfma_kernel<<<GB, 256, 0, stream>>>((const float4*)x, wtAll, nullptr, nullptr, tmp, N);
    aggregate_kernel<<<AB, 256, 0, stream>>>((const uint4*)tmp, colIdx, rowPtr, dinv, b1, hbuf, N);
    gemm_mfma_kernel<<<GB, 256, 0, stream>>>((const float4*)hbuf, wtAll + D * D, nullptr, nullptr, tmp, N);
    aggregate_kernel<<<AB, 256, 0, stream>>>((const uint4*)tmp, colIdx, rowPtr, dinv, b2, hbuf, N);
    bn_stats_kernel<<<512, 256, 0, stream>>>(hbuf, N, gsum1, gsq1);
    bn_finalize_kernel<<<1, 128, 0, stream>>>(gsum1, gsq1, g1, be1, (float)N, sc1, sh1);
    gemm_mfma_kernel<<<GB, 256, 0, stream>>>((const float4*)hbuf, wtAll + 2 * D * D, sc1, sh1, tmp, N);
    aggregate_kernel<<<AB, 256, 0, stream>>>((const uint4*)tmp, colIdx, rowPtr, dinv, b3, hbuf, N);
    bn_stats_kernel<<<512, 256, 0, stream>>>(hbuf, N, gsum2, gsq2);
    bn_finalize_kernel<<<1, 128, 0, stream>>>(gsum2, gsq2, g2, be2, (float)N, sc2, sh2);
    pool_kernel<<<G_GRAPHS, 128, 0, stream>>>(hbuf, sc2, sh2, gstart, pooled);
    classify_kernel<<<G_GRAPHS, 64, 0, stream>>>(pooled, fcw, fcb, (float*)d_out);
}

// Round 7
// 539.601 us; speedup vs baseline: 2.1927x; 1.1131x over previous
//
#include <hip/hip_runtime.h>
#include <hip/hip_bf16.h>
#include <math.h>

#define D 128
#define G_GRAPHS 512
#define C_CLASSES 10
#define BN_EPS 1e-5f
#define NBUCK_MAX 512     // supports N <= 131072 (bucket = node >> 8)
#define EDGE_CHUNK 4096
#define EPT 16            // EDGE_CHUNK / 256

typedef unsigned short u16;
typedef unsigned int u32;
typedef unsigned short ushort4_t __attribute__((ext_vector_type(4)));
typedef unsigned short ushort8_t __attribute__((ext_vector_type(8)));
typedef __bf16 bf16x8 __attribute__((ext_vector_type(8)));
typedef float floatx4 __attribute__((ext_vector_type(4)));
union B8 { ushort8_t u; bf16x8 b; };

__device__ __forceinline__ float bf_lo(u32 v) { return __uint_as_float(v << 16); }
__device__ __forceinline__ float bf_hi(u32 v) { return __uint_as_float(v & 0xffff0000u); }
__device__ __forceinline__ u16 f2bf(float f) {
    union { float f; u32 u; } x; x.f = f;
    u32 r = x.u + 0x7fff + ((x.u >> 16) & 1);  // RN-even
    return (u16)(r >> 16);
}
__device__ __forceinline__ u32 pack2bf(float a, float b) {
    return (u32)f2bf(a) | ((u32)f2bf(b) << 16);
}

// ============ CSR build: two-level counting sort ============

__global__ __launch_bounds__(256) void bucket_hist_kernel(
    const int* __restrict__ dst, int* __restrict__ bucketCnt, int E, int nbuck)
{
    __shared__ int h[NBUCK_MAX];
    int tid = threadIdx.x;
    for (int i = tid; i < NBUCK_MAX; i += 256) h[i] = 0;
    __syncthreads();
    for (int i = blockIdx.x * 256 + tid; i < E; i += gridDim.x * 256)
        atomicAdd(&h[dst[i] >> 8], 1);
    __syncthreads();
    for (int i = tid; i < nbuck; i += 256)
        if (h[i]) atomicAdd(&bucketCnt[i], h[i]);
}

__global__ void scan_buckets_kernel(
    const int* __restrict__ bucketCnt, int* __restrict__ bucketBase,
    int* __restrict__ bucketCursor, int* __restrict__ rowPtr, int nbuck, int N, int E)
{
    __shared__ int buf[2][512];
    int tid = threadIdx.x;
    int v = (tid < nbuck) ? bucketCnt[tid] : 0;
    buf[0][tid] = v;
    __syncthreads();
    int cur = 0;
    for (int off = 1; off < 512; off <<= 1) {
        buf[1 - cur][tid] = buf[cur][tid] + ((tid >= off) ? buf[cur][tid - off] : 0);
        cur ^= 1;
        __syncthreads();
    }
    if (tid < nbuck) {
        int b = buf[cur][tid] - v;  // exclusive
        bucketBase[tid] = b;
        bucketCursor[tid] = b;
    }
    if (tid == 0) { bucketBase[nbuck] = E; rowPtr[N] = E; }
}

// pairs packed: (src << 8) | (dst & 255)   [src < 2^17, fits 25 bits]
__global__ __launch_bounds__(256) void scatter_pairs_kernel(
    const int* __restrict__ src, const int* __restrict__ dst,
    int* __restrict__ bucketCursor, u32* __restrict__ pairs, int E)
{
    __shared__ int h[NBUCK_MAX];
    __shared__ int base[NBUCK_MAX];
    int tid = threadIdx.x;
    int e0 = blockIdx.x * EDGE_CHUNK;
    for (int i = tid; i < NBUCK_MAX; i += 256) h[i] = 0;
    __syncthreads();
    int s[EPT], d[EPT], r[EPT];
#pragma unroll
    for (int j = 0; j < EPT; ++j) {
        int i = e0 + j * 256 + tid;
        if (i < E) {
            s[j] = src[i];
            d[j] = dst[i];
            r[j] = atomicAdd(&h[d[j] >> 8], 1);
        } else {
            d[j] = -1;
        }
    }
    __syncthreads();
    for (int i = tid; i < NBUCK_MAX; i += 256)
        if (h[i]) base[i] = atomicAdd(&bucketCursor[i], h[i]);
    __syncthreads();
#pragma unroll
    for (int j = 0; j < EPT; ++j) {
        if (d[j] >= 0) {
            int b = d[j] >> 8;
            pairs[base[b] + r[j]] = ((u32)s[j] << 8) | (u32)(d[j] & 255);
        }
    }
}

__global__ __launch_bounds__(256) void bucket_sort_kernel(
    const u32* __restrict__ pairs, const int* __restrict__ bucketBase,
    int* __restrict__ colIdx, int* __restrict__ rowPtr, float* __restrict__ dinv, int N)
{
    __shared__ int h[256];
    __shared__ int cur[256];
    __shared__ int sbuf[2][256];
    int tid = threadIdx.x;
    int b = blockIdx.x;
    int s = bucketBase[b], e = bucketBase[b + 1];
    h[tid] = 0;
    __syncthreads();
    for (int i = s + tid; i < e; i += 256)
        atomicAdd(&h[pairs[i] & 255], 1);
    __syncthreads();
    int cnt = h[tid];
    sbuf[0][tid] = cnt;
    __syncthreads();
    int c = 0;
    for (int off = 1; off < 256; off <<= 1) {
        sbuf[1 - c][tid] = sbuf[c][tid] + ((tid >= off) ? sbuf[c][tid - off] : 0);
        c ^= 1;
        __syncthreads();
    }
    int excl = sbuf[c][tid] - cnt;
    int v = b * 256 + tid;
    if (v < N) {
        rowPtr[v] = s + excl;
        dinv[v] = rsqrtf((float)(cnt + 1));  // +1 self loop
    }
    cur[tid] = s + excl;
    __syncthreads();
    for (int i = s + tid; i < e; i += 256) {
        u32 p = pairs[i];
        int pos = atomicAdd(&cur[p & 255], 1);
        colIdx[pos] = (int)(p >> 8);
    }
}

// ---------------- graph segments: boundary detection on sorted batch ----------------
__global__ __launch_bounds__(256) void graph_bounds_kernel(
    const int* __restrict__ batch, int* __restrict__ gstart, int N)
{
    int i = blockIdx.x * 256 + threadIdx.x;
    if (i >= N) return;
    int b = batch[i];
    int prev = (i == 0) ? -1 : batch[i - 1];
    if (b != prev) {
        for (int g = prev + 1; g <= b; ++g) gstart[g] = i;  // covers empty graphs
    }
    if (i == N - 1) {
        for (int g = b + 1; g <= G_GRAPHS; ++g) gstart[g] = N;
    }
}

// ---------------- W pre-transpose+convert: Wt[n][k] bf16 ----------------
__global__ __launch_bounds__(256) void wconv_kernel(
    const float4* __restrict__ w1, const float4* __restrict__ w2,
    const float4* __restrict__ w3, u16* __restrict__ wtAll)
{
    const float4* W = (blockIdx.x == 0) ? w1 : (blockIdx.x == 1) ? w2 : w3;
    u16* Wt = wtAll + (size_t)blockIdx.x * D * D;
    int tid = threadIdx.x;
#pragma unroll
    for (int i = 0; i < 16; ++i) {
        int idx = tid + i * 256;        // = k*32 + c4
        int k = idx >> 5, c4 = idx & 31;
        float4 v = W[idx];
        Wt[(4 * c4 + 0) * D + k] = f2bf(v.x);
        Wt[(4 * c4 + 1) * D + k] = f2bf(v.y);
        Wt[(4 * c4 + 2) * D + k] = f2bf(v.z);
        Wt[(4 * c4 + 3) * D + k] = f2bf(v.w);
    }
}

// ---------------- MFMA GEMM core (shared epilogue convention) ----------------
// A-operand = W fragment (features), B-operand = X fragment (rows).
// D: row(quad*4+reg)=feature, col(lane&15)=x-row -> lane stores 4 consecutive
// features per tile as one 8B store.
#define XS_STRIDE 136

__device__ __forceinline__ void gemm_core_and_store(
    const u16* Xs, const u16* Ws, u16* __restrict__ Y, int row0, int nrows, int tid)
{
    int wid = tid >> 6, lane = tid & 63;
    int m = lane & 15, quad = lane >> 4;
    int xrow = wid * 16 + m;

    floatx4 acc[8] = {};
#pragma unroll
    for (int ks = 0; ks < 4; ++ks) {
        int kk = ks * 32 + quad * 8;
        B8 a;
        a.u = *(const ushort8_t*)&Xs[xrow * XS_STRIDE + kk];
#pragma unroll
        for (int t = 0; t < 8; ++t) {
            B8 b;
            b.u = *(const ushort8_t*)&Ws[(t * 16 + m) * XS_STRIDE + kk];
            acc[t] = __builtin_amdgcn_mfma_f32_16x16x32_bf16(b.b, a.b, acc[t], 0, 0, 0);
        }
    }
    int grow = row0 + xrow;
    if (grow < nrows) {
#pragma unroll
        for (int t = 0; t < 8; ++t) {
            ushort4_t o;
            o.x = f2bf(acc[t][0]); o.y = f2bf(acc[t][1]);
            o.z = f2bf(acc[t][2]); o.w = f2bf(acc[t][3]);
            *(ushort4_t*)&Y[(size_t)grow * D + t * 16 + quad * 4] = o;
        }
    }
}

__device__ __forceinline__ void stage_w(const u16* __restrict__ Wt, u16* Ws, int tid) {
    const ushort8_t* Wv = (const ushort8_t*)Wt;
#pragma unroll
    for (int i = 0; i < 8; ++i) {
        int idx = tid + i * 256;        // = n*16 + c8
        int n = idx >> 4, c8 = idx & 15;
        *(ushort8_t*)&Ws[n * XS_STRIDE + c8 * 8] = Wv[idx];
    }
}

// layer 1: X fp32
__global__ __launch_bounds__(256) void gemm_mfma_f32in_kernel(
    const float4* __restrict__ X, const u16* __restrict__ Wt,
    u16* __restrict__ Y, int nrows)
{
    __shared__ __align__(16) u16 Xs[64 * XS_STRIDE];
    __shared__ __align__(16) u16 Ws[128 * XS_STRIDE];
    int tid = threadIdx.x;
    int row0 = blockIdx.x * 64;
    stage_w(Wt, Ws, tid);
#pragma unroll
    for (int i = 0; i < 8; ++i) {
        int idx = tid + i * 256;        // = r*32 + c4
        int r = idx >> 5, c4 = idx & 31;
        int gr = row0 + r;
        float4 v = make_float4(0.f, 0.f, 0.f, 0.f);
        if (gr < nrows) v = X[(size_t)gr * 32 + c4];
        ushort4_t o;
        o.x = f2bf(v.x); o.y = f2bf(v.y); o.z = f2bf(v.z); o.w = f2bf(v.w);
        *(ushort4_t*)&Xs[r * XS_STRIDE + c4 * 4] = o;
    }
    __syncthreads();
    gemm_core_and_store(Xs, Ws, Y, row0, nrows, tid);
}

// layers 2/3: X bf16 (optional fused bn+relu on input)
__global__ __launch_bounds__(256) void gemm_mfma_bf16in_kernel(
    const uint4* __restrict__ X, const u16* __restrict__ Wt,
    const float* __restrict__ scale, const float* __restrict__ shift,
    u16* __restrict__ Y, int nrows)
{
    __shared__ __align__(16) u16 Xs[64 * XS_STRIDE];
    __shared__ __align__(16) u16 Ws[128 * XS_STRIDE];
    int tid = threadIdx.x;
    int row0 = blockIdx.x * 64;
    bool fuse = (scale != nullptr);
    stage_w(Wt, Ws, tid);
#pragma unroll
    for (int i = 0; i < 4; ++i) {
        int idx = tid + i * 256;        // = r*16 + c8
        int r = idx >> 4, c8 = idx & 15;
        int gr = row0 + r;
        uint4 v = make_uint4(0, 0, 0, 0);
        if (gr < nrows) v = X[(size_t)gr * 16 + c8];
        if (fuse) {
            int k = c8 * 8;
            v.x = pack2bf(fmaxf(bf_lo(v.x) * scale[k]     + shift[k],     0.f),
                          fmaxf(bf_hi(v.x) * scale[k + 1] + shift[k + 1], 0.f));
            v.y = pack2bf(fmaxf(bf_lo(v.y) * scale[k + 2] + shift[k + 2], 0.f),
                          fmaxf(bf_hi(v.y) * scale[k + 3] + shift[k + 3], 0.f));
            v.z = pack2bf(fmaxf(bf_lo(v.z) * scale[k + 4] + shift[k + 4], 0.f),
                          fmaxf(bf_hi(v.z) * scale[k + 5] + shift[k + 5], 0.f));
            v.w = pack2bf(fmaxf(bf_lo(v.w) * scale[k + 6] + shift[k + 6], 0.f),
                          fmaxf(bf_hi(v.w) * scale[k + 7] + shift[k + 7], 0.f));
        }
        *(uint4*)&Xs[r * XS_STRIDE + c8 * 8] = v;
    }
    __syncthreads();
    gemm_core_and_store(Xs, Ws, Y, row0, nrows, tid);
}

// ---------------- aggregation: 4 edges/iter, dwordx4 gathers, bf16 out ----------------
__global__ __launch_bounds__(256) void aggregate_kernel(
    const uint4* __restrict__ T, const int* __restrict__ colIdx,
    const int* __restrict__ rowPtr, const float* __restrict__ dinv,
    const float* __restrict__ bias, u32* __restrict__ outH, int n)
{
    int wid = threadIdx.x >> 6;
    int lane = threadIdx.x & 63;
    int row = blockIdx.x * 4 + wid;
    if (row >= n) return;
    int fg = lane & 15;
    int eg = lane >> 4;

    float dr = dinv[row];
    float acc[8] = {};

    if (eg == 0) {
        uint4 sv = T[(size_t)row * 16 + fg];
        acc[0] = dr * bf_lo(sv.x); acc[1] = dr * bf_hi(sv.x);
        acc[2] = dr * bf_lo(sv.y); acc[3] = dr * bf_hi(sv.y);
        acc[4] = dr * bf_lo(sv.z); acc[5] = dr * bf_hi(sv.z);
        acc[6] = dr * bf_lo(sv.w); acc[7] = dr * bf_hi(sv.w);
    }

    int s = rowPtr[row], e = rowPtr[row + 1];
    for (int j0 = s; j0 < e; j0 += 64) {
        int m = e - j0;
        if (m > 64) m = 64;
        int u = row;
        float du = 0.f;
        if (lane < m) {
            u = colIdx[j0 + lane];
            du = dinv[u];
        }
        int nt = (m + 3) >> 2;
        for (int t = 0; t < nt; ++t) {
            int idx = t * 4 + eg;
            int uu = __shfl(u, idx);
            float duu = __shfl(du, idx);
            uint4 tw = T[(size_t)uu * 16 + fg];
            acc[0] += duu * bf_lo(tw.x); acc[1] += duu * bf_hi(tw.x);
            acc[2] += duu * bf_lo(tw.y); acc[3] += duu * bf_hi(tw.y);
            acc[4] += duu * bf_lo(tw.z); acc[5] += duu * bf_hi(tw.z);
            acc[6] += duu * bf_lo(tw.w); acc[7] += duu * bf_hi(tw.w);
        }
    }

#pragma unroll
    for (int off = 16; off < 64; off <<= 1) {
#pragma unroll
        for (int i = 0; i < 8; ++i) acc[i] += __shfl_xor(acc[i], off);
    }

    const float2* bp = (const float2*)bias;
    int pidx = fg * 4 + eg;
    float2 b = bp[pidx];
    float ox = fmaxf(dr * acc[eg * 2] + b.x, 0.f);
    float oy = fmaxf(dr * acc[eg * 2 + 1] + b.y, 0.f);
    outH[(size_t)row * 64 + pidx] = pack2bf(ox, oy);
}

// ---------------- batchnorm stats (bf16 input, 2 cols/thread, 4 rows/block-iter) ----
__global__ __launch_bounds__(256) void bn_stats_kernel(
    const u32* __restrict__ H, int n, float* __restrict__ gsum, float* __restrict__ gsq)
{
    int tid = threadIdx.x;
    int c = tid & 63, rr = tid >> 6;
    float sA = 0.f, sA2 = 0.f, sB = 0.f, sB2 = 0.f;
    for (int row = blockIdx.x * 4 + rr; row < n; row += gridDim.x * 4) {
        u32 v = H[(size_t)row * 64 + c];
        float a = bf_lo(v), b = bf_hi(v);
        sA += a; sA2 += a * a; sB += b; sB2 += b * b;
    }
    __shared__ float shA[256], shA2[256], shB[256], shB2[256];
    shA[tid] = sA; shA2[tid] = sA2; shB[tid] = sB; shB2[tid] = sB2;
    __syncthreads();
    if (tid < 64) {
        float tA = shA[tid] + shA[tid + 64] + shA[tid + 128] + shA[tid + 192];
        float tA2 = shA2[tid] + shA2[tid + 64] + shA2[tid + 128] + shA2[tid + 192];
        float tB = shB[tid] + shB[tid + 64] + shB[tid + 128] + shB[tid + 192];
        float tB2 = shB2[tid] + shB2[tid + 64] + shB2[tid + 128] + shB2[tid + 192];
        atomicAdd(&gsum[2 * c], tA);
        atomicAdd(&gsq[2 * c], tA2);
        atomicAdd(&gsum[2 * c + 1], tB);
        atomicAdd(&gsq[2 * c + 1], tB2);
    }
}

__global__ void bn_finalize_kernel(const float* __restrict__ gsum, const float* __restrict__ gsq,
                                   const float* __restrict__ gamma, const float* __restrict__ beta,
                                   float n, float* __restrict__ scale, float* __restrict__ shift)
{
    int c = threadIdx.x;  // 128
    float mu = gsum[c] / n;
    float var = gsq[c] / n - mu * mu;
    float sc = gamma[c] * rsqrtf(var + BN_EPS);
    scale[c] = sc;
    shift[c] = beta[c] - mu * sc;
}

// ---------------- pooling (fused bn2+relu), bf16 input, 4-way row split ----------------
__global__ __launch_bounds__(256) void pool_kernel(
    const u32* __restrict__ H, const float* __restrict__ scale, const float* __restrict__ shift,
    const int* __restrict__ gstart, float* __restrict__ pooled)
{
    int g = blockIdx.x;
    int tid = threadIdx.x;
    int c = tid & 63, q = tid >> 6;
    int s = gstart[g], cnt = gstart[g + 1] - s;
    float scA = scale[2 * c], shA = shift[2 * c];
    float scB = scale[2 * c + 1], shB = shift[2 * c + 1];
    float aA = 0.f, aB = 0.f;
    for (int i = q; i < cnt; i += 4) {
        u32 v = H[(size_t)(s + i) * 64 + c];
        aA += fmaxf(bf_lo(v) * scA + shA, 0.f);
        aB += fmaxf(bf_hi(v) * scB + shB, 0.f);
    }
    __shared__ float shAa[256], shBb[256];
    shAa[tid] = aA; shBb[tid] = aB;
    __syncthreads();
    if (tid < 64) {
        float tA = shAa[tid] + shAa[tid + 64] + shAa[tid + 128] + shAa[tid + 192];
        float tB = shBb[tid] + shBb[tid + 64] + shBb[tid + 128] + shBb[tid + 192];
        float inv = 1.f / (float)(cnt > 1 ? cnt : 1);
        ((float2*)pooled)[(size_t)g * 64 + c] = make_float2(tA * inv, tB * inv);
    }
}

// ---------------- classifier + log_softmax ----------------
__global__ __launch_bounds__(64) void classify_kernel(
    const float* __restrict__ pooled, const float* __restrict__ fcw,
    const float* __restrict__ fcb, float* __restrict__ out)
{
    int g = blockIdx.x;
    int tid = threadIdx.x;  // 64
    __shared__ float prow[D];
    __shared__ float lg[C_CLASSES];
    prow[tid] = pooled[(size_t)g * D + tid];
    prow[tid + 64] = pooled[(size_t)g * D + 64 + tid];
    __syncthreads();
    if (tid < C_CLASSES) {
        float s = fcb[tid];
        for (int d = 0; d < D; ++d) s += prow[d] * fcw[d * C_CLASSES + tid];
        lg[tid] = s;
    }
    __syncthreads();
    if (tid == 0) {
        float m = -1e30f;
        for (int c = 0; c < C_CLASSES; ++c) m = fmaxf(m, lg[c]);
        float se = 0.f;
        for (int c = 0; c < C_CLASSES; ++c) se += expf(lg[c] - m);
        float lse = m + logf(se);
        for (int c = 0; c < C_CLASSES; ++c) out[(size_t)g * C_CLASSES + c] = lg[c] - lse;
    }
}

extern "C" void kernel_launch(void* const* d_in, const int* in_sizes, int n_in,
                              void* d_out, int out_size, void* d_ws, size_t ws_size,
                              hipStream_t stream) {
    const float* x   = (const float*)d_in[0];
    const int* ei    = (const int*)d_in[1];
    const int* batch = (const int*)d_in[2];
    const float* w1  = (const float*)d_in[3];
    const float* b1  = (const float*)d_in[4];
    const float* w2  = (const float*)d_in[5];
    const float* b2  = (const float*)d_in[6];
    const float* w3  = (const float*)d_in[7];
    const float* b3  = (const float*)d_in[8];
    const float* g1  = (const float*)d_in[9];
    const float* be1 = (const float*)d_in[10];
    const float* g2  = (const float*)d_in[11];
    const float* be2 = (const float*)d_in[12];
    const float* fcw = (const float*)d_in[13];
    const float* fcb = (const float*)d_in[14];

    const int N = in_sizes[0] / D;
    const int E = in_sizes[1] / 2;
    const int* src = ei;
    const int* dst = ei + E;
    const int nbuck = (N + 255) >> 8;

    char* p = (char*)d_ws;
    auto alloc = [&](size_t bytes) -> void* {
        void* r = (void*)p;
        p += (bytes + 255) & ~(size_t)255;
        return r;
    };
    float* dinv     = (float*)alloc((size_t)N * 4);
    int*   rowPtr   = (int*)alloc((size_t)(N + 1) * 4);
    int*   colIdx   = (int*)alloc((size_t)E * 4);
    u32*   pairs    = (u32*)alloc((size_t)E * 4);
    int*   bucketCnt    = (int*)alloc(NBUCK_MAX * 4);
    int*   bucketBase   = (int*)alloc((NBUCK_MAX + 1) * 4);
    int*   bucketCursor = (int*)alloc(NBUCK_MAX * 4);
    int*   gstart  = (int*)alloc((G_GRAPHS + 1) * 4);
    float* statsacc= (float*)alloc(4 * D * 4);
    float* gsum1 = statsacc, *gsq1 = statsacc + D, *gsum2 = statsacc + 2 * D, *gsq2 = statsacc + 3 * D;
    float* sc1     = (float*)alloc(D * 4);
    float* sh1     = (float*)alloc(D * 4);
    float* sc2     = (float*)alloc(D * 4);
    float* sh2     = (float*)alloc(D * 4);
    float* pooled  = (float*)alloc((size_t)G_GRAPHS * D * 4);
    u16*   wtAll   = (u16*)alloc((size_t)3 * D * D * 2);   // bf16 W^T x3
    u16*   tmp     = (u16*)alloc((size_t)N * D * 2);       // bf16 gemm out
    u16*   hbuf    = (u16*)alloc((size_t)N * D * 2);       // bf16 agg out

    hipMemsetAsync(bucketCnt, 0, NBUCK_MAX * 4, stream);
    hipMemsetAsync(statsacc, 0, 4 * D * 4, stream);

    // ---- graph structure ----
    bucket_hist_kernel<<<512, 256, 0, stream>>>(dst, bucketCnt, E, nbuck);
    scan_buckets_kernel<<<1, 512, 0, stream>>>(bucketCnt, bucketBase, bucketCursor, rowPtr, nbuck, N, E);
    scatter_pairs_kernel<<<(E + EDGE_CHUNK - 1) / EDGE_CHUNK, 256, 0, stream>>>(src, dst, bucketCursor, pairs, E);
    bucket_sort_kernel<<<nbuck, 256, 0, stream>>>(pairs, bucketBase, colIdx, rowPtr, dinv, N);
    graph_bounds_kernel<<<(N + 255) / 256, 256, 0, stream>>>(batch, gstart, N);
    wconv_kernel<<<3, 256, 0, stream>>>((const float4*)w1, (const float4*)w2, (const float4*)w3, wtAll);

    const int GB = (N + 63) / 64;
    const int AB = (N + 3) / 4;

    gemm_mfma_f32in_kernel<<<GB, 256, 0, stream>>>((const float4*)x, wtAll, tmp, N);
    aggregate_kernel<<<AB, 256, 0, stream>>>((const uint4*)tmp, colIdx, rowPtr, dinv, b1, (u32*)hbuf, N);
    gemm_mfma_bf16in_kernel<<<GB, 256, 0, stream>>>((const uint4*)hbuf, wtAll + D * D, nullptr, nullptr, tmp, N);
    aggregate_kernel<<<AB, 256, 0, stream>>>((const uint4*)tmp, colIdx, rowPtr, dinv, b2, (u32*)hbuf, N);
    bn_stats_kernel<<<256, 256, 0, stream>>>((const u32*)hbuf, N, gsum1, gsq1);
    bn_finalize_kernel<<<1, 128, 0, stream>>>(gsum1, gsq1, g1, be1, (float)N, sc1, sh1);
    gemm_mfma_bf16in_kernel<<<GB, 256, 0, stream>>>((const uint4*)hbuf, wtAll + 2 * D * D, sc1, sh1, tmp, N);
    aggregate_kernel<<<AB, 256, 0, stream>>>((const uint4*)tmp, colIdx, rowPtr, dinv, b3, (u32*)hbuf, N);
    bn_stats_kernel<<<256, 256, 0, stream>>>((const u32*)hbuf, N, gsum2, gsq2);
    bn_finalize_kernel<<<1, 128, 0, stream>>>(gsum2, gsq2, g2, be2, (float)N, sc2, sh2);
    pool_kernel<<<G_GRAPHS, 256, 0, stream>>>((const u32*)hbuf, sc2, sh2, gstart, pooled);
    classify_kernel<<<G_GRAPHS, 64, 0, stream>>>(pooled, fcw, fcb, (float*)d_out);
}

// Round 8
// 520.710 us; speedup vs baseline: 2.2722x; 1.0363x over previous
//
#include <hip/hip_runtime.h>
#include <hip/hip_bf16.h>
#include <math.h>

#define D 128
#define G_GRAPHS 512
#define C_CLASSES 10
#define BN_EPS 1e-5f
#define NBUCK_MAX 512     // supports N <= 131072 (bucket = node >> 8)
#define EDGE_CHUNK 4096
#define EPT 16            // EDGE_CHUNK / 256

typedef unsigned short u16;
typedef unsigned int u32;
typedef unsigned short ushort4_t __attribute__((ext_vector_type(4)));
typedef unsigned short ushort8_t __attribute__((ext_vector_type(8)));
typedef __bf16 bf16x8 __attribute__((ext_vector_type(8)));
typedef float floatx4 __attribute__((ext_vector_type(4)));
union B8 { ushort8_t u; bf16x8 b; };

__device__ __forceinline__ float bf_lo(u32 v) { return __uint_as_float(v << 16); }
__device__ __forceinline__ float bf_hi(u32 v) { return __uint_as_float(v & 0xffff0000u); }
__device__ __forceinline__ u16 f2bf(float f) {
    union { float f; u32 u; } x; x.f = f;
    u32 r = x.u + 0x7fff + ((x.u >> 16) & 1);  // RN-even
    return (u16)(r >> 16);
}
__device__ __forceinline__ u32 pack2bf(float a, float b) {
    return (u32)f2bf(a) | ((u32)f2bf(b) << 16);
}

// ============ CSR build: two-level counting sort ============

__global__ __launch_bounds__(256) void bucket_hist_kernel(
    const int* __restrict__ dst, int* __restrict__ bucketCnt, int E, int nbuck)
{
    __shared__ int h[NBUCK_MAX];
    int tid = threadIdx.x;
    for (int i = tid; i < NBUCK_MAX; i += 256) h[i] = 0;
    __syncthreads();
    for (int i = blockIdx.x * 256 + tid; i < E; i += gridDim.x * 256)
        atomicAdd(&h[dst[i] >> 8], 1);
    __syncthreads();
    for (int i = tid; i < nbuck; i += 256)
        if (h[i]) atomicAdd(&bucketCnt[i], h[i]);
}

__global__ void scan_buckets_kernel(
    const int* __restrict__ bucketCnt, int* __restrict__ bucketBase,
    int* __restrict__ bucketCursor, int* __restrict__ rowPtr, int nbuck, int N, int E)
{
    __shared__ int buf[2][512];
    int tid = threadIdx.x;
    int v = (tid < nbuck) ? bucketCnt[tid] : 0;
    buf[0][tid] = v;
    __syncthreads();
    int cur = 0;
    for (int off = 1; off < 512; off <<= 1) {
        buf[1 - cur][tid] = buf[cur][tid] + ((tid >= off) ? buf[cur][tid - off] : 0);
        cur ^= 1;
        __syncthreads();
    }
    if (tid < nbuck) {
        int b = buf[cur][tid] - v;  // exclusive
        bucketBase[tid] = b;
        bucketCursor[tid] = b;
    }
    if (tid == 0) { bucketBase[nbuck] = E; rowPtr[N] = E; }
}

// pairs packed: (src << 8) | (dst & 255)   [src < 2^17, fits 25 bits]
__global__ __launch_bounds__(256) void scatter_pairs_kernel(
    const int* __restrict__ src, const int* __restrict__ dst,
    int* __restrict__ bucketCursor, u32* __restrict__ pairs, int E)
{
    __shared__ int h[NBUCK_MAX];
    __shared__ int base[NBUCK_MAX];
    int tid = threadIdx.x;
    int e0 = blockIdx.x * EDGE_CHUNK;
    for (int i = tid; i < NBUCK_MAX; i += 256) h[i] = 0;
    __syncthreads();
    int s[EPT], d[EPT], r[EPT];
#pragma unroll
    for (int j = 0; j < EPT; ++j) {
        int i = e0 + j * 256 + tid;
        if (i < E) {
            s[j] = src[i];
            d[j] = dst[i];
            r[j] = atomicAdd(&h[d[j] >> 8], 1);
        } else {
            d[j] = -1;
        }
    }
    __syncthreads();
    for (int i = tid; i < NBUCK_MAX; i += 256)
        if (h[i]) base[i] = atomicAdd(&bucketCursor[i], h[i]);
    __syncthreads();
#pragma unroll
    for (int j = 0; j < EPT; ++j) {
        if (d[j] >= 0) {
            int b = d[j] >> 8;
            pairs[base[b] + r[j]] = ((u32)s[j] << 8) | (u32)(d[j] & 255);
        }
    }
}

__global__ __launch_bounds__(256) void bucket_sort_kernel(
    const u32* __restrict__ pairs, const int* __restrict__ bucketBase,
    int* __restrict__ colIdx, int* __restrict__ rowPtr, float* __restrict__ dinv, int N)
{
    __shared__ int h[256];
    __shared__ int cur[256];
    __shared__ int sbuf[2][256];
    int tid = threadIdx.x;
    int b = blockIdx.x;
    int s = bucketBase[b], e = bucketBase[b + 1];
    h[tid] = 0;
    __syncthreads();
    for (int i = s + tid; i < e; i += 256)
        atomicAdd(&h[pairs[i] & 255], 1);
    __syncthreads();
    int cnt = h[tid];
    sbuf[0][tid] = cnt;
    __syncthreads();
    int c = 0;
    for (int off = 1; off < 256; off <<= 1) {
        sbuf[1 - c][tid] = sbuf[c][tid] + ((tid >= off) ? sbuf[c][tid - off] : 0);
        c ^= 1;
        __syncthreads();
    }
    int excl = sbuf[c][tid] - cnt;
    int v = b * 256 + tid;
    if (v < N) {
        rowPtr[v] = s + excl;
        dinv[v] = rsqrtf((float)(cnt + 1));  // +1 self loop
    }
    cur[tid] = s + excl;
    __syncthreads();
    for (int i = s + tid; i < e; i += 256) {
        u32 p = pairs[i];
        int pos = atomicAdd(&cur[p & 255], 1);
        colIdx[pos] = (int)(p >> 8);
    }
}

// ---------------- graph segments: boundary detection on sorted batch ----------------
__global__ __launch_bounds__(256) void graph_bounds_kernel(
    const int* __restrict__ batch, int* __restrict__ gstart, int N)
{
    int i = blockIdx.x * 256 + threadIdx.x;
    if (i >= N) return;
    int b = batch[i];
    int prev = (i == 0) ? -1 : batch[i - 1];
    if (b != prev) {
        for (int g = prev + 1; g <= b; ++g) gstart[g] = i;  // covers empty graphs
    }
    if (i == N - 1) {
        for (int g = b + 1; g <= G_GRAPHS; ++g) gstart[g] = N;
    }
}

// ---------------- W pre-transpose+convert: Wt[n][k] bf16 ----------------
__global__ __launch_bounds__(256) void wconv_kernel(
    const float4* __restrict__ w1, const float4* __restrict__ w2,
    const float4* __restrict__ w3, u16* __restrict__ wtAll)
{
    const float4* W = (blockIdx.x == 0) ? w1 : (blockIdx.x == 1) ? w2 : w3;
    u16* Wt = wtAll + (size_t)blockIdx.x * D * D;
    int tid = threadIdx.x;
#pragma unroll
    for (int i = 0; i < 16; ++i) {
        int idx = tid + i * 256;        // = k*32 + c4
        int k = idx >> 5, c4 = idx & 31;
        float4 v = W[idx];
        Wt[(4 * c4 + 0) * D + k] = f2bf(v.x);
        Wt[(4 * c4 + 1) * D + k] = f2bf(v.y);
        Wt[(4 * c4 + 2) * D + k] = f2bf(v.z);
        Wt[(4 * c4 + 3) * D + k] = f2bf(v.w);
    }
}

// ---------------- MFMA GEMM core (A=W frag, B=X frag; 8B stores) ----------------
#define XS_STRIDE 136

__device__ __forceinline__ void gemm_core_and_store(
    const u16* Xs, const u16* Ws, u16* __restrict__ Y, int row0, int nrows, int tid)
{
    int wid = tid >> 6, lane = tid & 63;
    int m = lane & 15, quad = lane >> 4;
    int xrow = wid * 16 + m;

    floatx4 acc[8] = {};
#pragma unroll
    for (int ks = 0; ks < 4; ++ks) {
        int kk = ks * 32 + quad * 8;
        B8 a;
        a.u = *(const ushort8_t*)&Xs[xrow * XS_STRIDE + kk];
#pragma unroll
        for (int t = 0; t < 8; ++t) {
            B8 b;
            b.u = *(const ushort8_t*)&Ws[(t * 16 + m) * XS_STRIDE + kk];
            acc[t] = __builtin_amdgcn_mfma_f32_16x16x32_bf16(b.b, a.b, acc[t], 0, 0, 0);
        }
    }
    int grow = row0 + xrow;
    if (grow < nrows) {
#pragma unroll
        for (int t = 0; t < 8; ++t) {
            ushort4_t o;
            o.x = f2bf(acc[t][0]); o.y = f2bf(acc[t][1]);
            o.z = f2bf(acc[t][2]); o.w = f2bf(acc[t][3]);
            *(ushort4_t*)&Y[(size_t)grow * D + t * 16 + quad * 4] = o;
        }
    }
}

__device__ __forceinline__ void stage_w(const u16* __restrict__ Wt, u16* Ws, int tid) {
    const ushort8_t* Wv = (const ushort8_t*)Wt;
#pragma unroll
    for (int i = 0; i < 8; ++i) {
        int idx = tid + i * 256;        // = n*16 + c8
        int n = idx >> 4, c8 = idx & 15;
        *(ushort8_t*)&Ws[n * XS_STRIDE + c8 * 8] = Wv[idx];
    }
}

// layer 1: X fp32
__global__ __launch_bounds__(256) void gemm_mfma_f32in_kernel(
    const float4* __restrict__ X, const u16* __restrict__ Wt,
    u16* __restrict__ Y, int nrows)
{
    __shared__ __align__(16) u16 Xs[64 * XS_STRIDE];
    __shared__ __align__(16) u16 Ws[128 * XS_STRIDE];
    int tid = threadIdx.x;
    int row0 = blockIdx.x * 64;
    stage_w(Wt, Ws, tid);
#pragma unroll
    for (int i = 0; i < 8; ++i) {
        int idx = tid + i * 256;        // = r*32 + c4
        int r = idx >> 5, c4 = idx & 31;
        int gr = row0 + r;
        float4 v = make_float4(0.f, 0.f, 0.f, 0.f);
        if (gr < nrows) v = X[(size_t)gr * 32 + c4];
        ushort4_t o;
        o.x = f2bf(v.x); o.y = f2bf(v.y); o.z = f2bf(v.z); o.w = f2bf(v.w);
        *(ushort4_t*)&Xs[r * XS_STRIDE + c4 * 4] = o;
    }
    __syncthreads();
    gemm_core_and_store(Xs, Ws, Y, row0, nrows, tid);
}

// layers 2/3: X bf16 (optional fused bn+relu on input)
__global__ __launch_bounds__(256) void gemm_mfma_bf16in_kernel(
    const uint4* __restrict__ X, const u16* __restrict__ Wt,
    const float* __restrict__ scale, const float* __restrict__ shift,
    u16* __restrict__ Y, int nrows)
{
    __shared__ __align__(16) u16 Xs[64 * XS_STRIDE];
    __shared__ __align__(16) u16 Ws[128 * XS_STRIDE];
    int tid = threadIdx.x;
    int row0 = blockIdx.x * 64;
    bool fuse = (scale != nullptr);
    stage_w(Wt, Ws, tid);
#pragma unroll
    for (int i = 0; i < 4; ++i) {
        int idx = tid + i * 256;        // = r*16 + c8
        int r = idx >> 4, c8 = idx & 15;
        int gr = row0 + r;
        uint4 v = make_uint4(0, 0, 0, 0);
        if (gr < nrows) v = X[(size_t)gr * 16 + c8];
        if (fuse) {
            int k = c8 * 8;
            v.x = pack2bf(fmaxf(bf_lo(v.x) * scale[k]     + shift[k],     0.f),
                          fmaxf(bf_hi(v.x) * scale[k + 1] + shift[k + 1], 0.f));
            v.y = pack2bf(fmaxf(bf_lo(v.y) * scale[k + 2] + shift[k + 2], 0.f),
                          fmaxf(bf_hi(v.y) * scale[k + 3] + shift[k + 3], 0.f));
            v.z = pack2bf(fmaxf(bf_lo(v.z) * scale[k + 4] + shift[k + 4], 0.f),
                          fmaxf(bf_hi(v.z) * scale[k + 5] + shift[k + 5], 0.f));
            v.w = pack2bf(fmaxf(bf_lo(v.w) * scale[k + 6] + shift[k + 6], 0.f),
                          fmaxf(bf_hi(v.w) * scale[k + 7] + shift[k + 7], 0.f));
        }
        *(uint4*)&Xs[r * XS_STRIDE + c8 * 8] = v;
    }
    __syncthreads();
    gemm_core_and_store(Xs, Ws, Y, row0, nrows, tid);
}

// ---------------- aggregation v3: 4-deep gather batches per 16-lane group ----------------
#define ACC8(tw, duu)                                              \
    acc[0] += (duu) * bf_lo((tw).x); acc[1] += (duu) * bf_hi((tw).x); \
    acc[2] += (duu) * bf_lo((tw).y); acc[3] += (duu) * bf_hi((tw).y); \
    acc[4] += (duu) * bf_lo((tw).z); acc[5] += (duu) * bf_hi((tw).z); \
    acc[6] += (duu) * bf_lo((tw).w); acc[7] += (duu) * bf_hi((tw).w);

__global__ __launch_bounds__(256) void aggregate_kernel(
    const uint4* __restrict__ T, const int* __restrict__ colIdx,
    const int* __restrict__ rowPtr, const float* __restrict__ dinv,
    const float* __restrict__ bias, u32* __restrict__ outH, int n)
{
    int wid = threadIdx.x >> 6;
    int lane = threadIdx.x & 63;
    int row = blockIdx.x * 4 + wid;
    if (row >= n) return;
    int fg = lane & 15;
    int eg = lane >> 4;

    float dr = dinv[row];
    float acc[8] = {};

    if (eg == 0) {
        uint4 sv = T[(size_t)row * 16 + fg];
        acc[0] = dr * bf_lo(sv.x); acc[1] = dr * bf_hi(sv.x);
        acc[2] = dr * bf_lo(sv.y); acc[3] = dr * bf_hi(sv.y);
        acc[4] = dr * bf_lo(sv.z); acc[5] = dr * bf_hi(sv.z);
        acc[6] = dr * bf_lo(sv.w); acc[7] = dr * bf_hi(sv.w);
    }

    int s = rowPtr[row], e = rowPtr[row + 1];
    for (int j0 = s; j0 < e; j0 += 64) {
        int m = e - j0;
        if (m > 64) m = 64;
        int u = row;        // inactive lanes: row's own (L2-hot) line, weight 0
        float du = 0.f;
        if (lane < m) {
            u = colIdx[j0 + lane];
            du = dinv[u];
        }
        int nc = (m + 15) >> 4;  // 16-edge sub-chunks; 4 edges per group per sub-chunk
        for (int c = 0; c < nc; ++c) {
            int b0 = c * 16 + eg;
            int u0 = __shfl(u, b0);      int u1 = __shfl(u, b0 + 4);
            int u2 = __shfl(u, b0 + 8);  int u3 = __shfl(u, b0 + 12);
            float d0 = __shfl(du, b0);      float d1 = __shfl(du, b0 + 4);
            float d2 = __shfl(du, b0 + 8);  float d3 = __shfl(du, b0 + 12);
            uint4 t0 = T[(size_t)u0 * 16 + fg];
            uint4 t1 = T[(size_t)u1 * 16 + fg];
            uint4 t2 = T[(size_t)u2 * 16 + fg];
            uint4 t3 = T[(size_t)u3 * 16 + fg];
            ACC8(t0, d0); ACC8(t1, d1); ACC8(t2, d2); ACC8(t3, d3);
        }
    }

#pragma unroll
    for (int off = 16; off < 64; off <<= 1) {
#pragma unroll
        for (int i = 0; i < 8; ++i) acc[i] += __shfl_xor(acc[i], off);
    }

    const float2* bp = (const float2*)bias;
    int pidx = fg * 4 + eg;
    float2 b = bp[pidx];
    float ox = fmaxf(dr * acc[eg * 2] + b.x, 0.f);
    float oy = fmaxf(dr * acc[eg * 2 + 1] + b.y, 0.f);
    outH[(size_t)row * 64 + pidx] = pack2bf(ox, oy);
}

// ---------------- batchnorm stats (bf16 input) ----------------
__global__ __launch_bounds__(256) void bn_stats_kernel(
    const u32* __restrict__ H, int n, float* __restrict__ gsum, float* __restrict__ gsq)
{
    int tid = threadIdx.x;
    int c = tid & 63, rr = tid >> 6;
    float sA = 0.f, sA2 = 0.f, sB = 0.f, sB2 = 0.f;
    for (int row = blockIdx.x * 4 + rr; row < n; row += gridDim.x * 4) {
        u32 v = H[(size_t)row * 64 + c];
        float a = bf_lo(v), b = bf_hi(v);
        sA += a; sA2 += a * a; sB += b; sB2 += b * b;
    }
    __shared__ float shA[256], shA2[256], shB[256], shB2[256];
    shA[tid] = sA; shA2[tid] = sA2; shB[tid] = sB; shB2[tid] = sB2;
    __syncthreads();
    if (tid < 64) {
        float tA = shA[tid] + shA[tid + 64] + shA[tid + 128] + shA[tid + 192];
        float tA2 = shA2[tid] + shA2[tid + 64] + shA2[tid + 128] + shA2[tid + 192];
        float tB = shB[tid] + shB[tid + 64] + shB[tid + 128] + shB[tid + 192];
        float tB2 = shB2[tid] + shB2[tid + 64] + shB2[tid + 128] + shB2[tid + 192];
        atomicAdd(&gsum[2 * c], tA);
        atomicAdd(&gsq[2 * c], tA2);
        atomicAdd(&gsum[2 * c + 1], tB);
        atomicAdd(&gsq[2 * c + 1], tB2);
    }
}

__global__ void bn_finalize_kernel(const float* __restrict__ gsum, const float* __restrict__ gsq,
                                   const float* __restrict__ gamma, const float* __restrict__ beta,
                                   float n, float* __restrict__ scale, float* __restrict__ shift)
{
    int c = threadIdx.x;  // 128
    float mu = gsum[c] / n;
    float var = gsq[c] / n - mu * mu;
    float sc = gamma[c] * rsqrtf(var + BN_EPS);
    scale[c] = sc;
    shift[c] = beta[c] - mu * sc;
}

// ---------------- pooling (fused bn2+relu), bf16 input ----------------
__global__ __launch_bounds__(256) void pool_kernel(
    const u32* __restrict__ H, const float* __restrict__ scale, const float* __restrict__ shift,
    const int* __restrict__ gstart, float* __restrict__ pooled)
{
    int g = blockIdx.x;
    int tid = threadIdx.x;
    int c = tid & 63, q = tid >> 6;
    int s = gstart[g], cnt = gstart[g + 1] - s;
    float scA = scale[2 * c], shA = shift[2 * c];
    float scB = scale[2 * c + 1], shB = shift[2 * c + 1];
    float aA = 0.f, aB = 0.f;
    for (int i = q; i < cnt; i += 4) {
        u32 v = H[(size_t)(s + i) * 64 + c];
        aA += fmaxf(bf_lo(v) * scA + shA, 0.f);
        aB += fmaxf(bf_hi(v) * scB + shB, 0.f);
    }
    __shared__ float shAa[256], shBb[256];
    shAa[tid] = aA; shBb[tid] = aB;
    __syncthreads();
    if (tid < 64) {
        float tA = shAa[tid] + shAa[tid + 64] + shAa[tid + 128] + shAa[tid + 192];
        float tB = shBb[tid] + shBb[tid + 64] + shBb[tid + 128] + shBb[tid + 192];
        float inv = 1.f / (float)(cnt > 1 ? cnt : 1);
        ((float2*)pooled)[(size_t)g * 64 + c] = make_float2(tA * inv, tB * inv);
    }
}

// ---------------- classifier + log_softmax ----------------
__global__ __launch_bounds__(64) void classify_kernel(
    const float* __restrict__ pooled, const float* __restrict__ fcw,
    const float* __restrict__ fcb, float* __restrict__ out)
{
    int g = blockIdx.x;
    int tid = threadIdx.x;  // 64
    __shared__ float prow[D];
    __shared__ float lg[C_CLASSES];
    prow[tid] = pooled[(size_t)g * D + tid];
    prow[tid + 64] = pooled[(size_t)g * D + 64 + tid];
    __syncthreads();
    if (tid < C_CLASSES) {
        float s = fcb[tid];
        for (int d = 0; d < D; ++d) s += prow[d] * fcw[d * C_CLASSES + tid];
        lg[tid] = s;
    }
    __syncthreads();
    if (tid == 0) {
        float m = -1e30f;
        for (int c = 0; c < C_CLASSES; ++c) m = fmaxf(m, lg[c]);
        float se = 0.f;
        for (int c = 0; c < C_CLASSES; ++c) se += expf(lg[c] - m);
        float lse = m + logf(se);
        for (int c = 0; c < C_CLASSES; ++c) out[(size_t)g * C_CLASSES + c] = lg[c] - lse;
    }
}

extern "C" void kernel_launch(void* const* d_in, const int* in_sizes, int n_in,
                              void* d_out, int out_size, void* d_ws, size_t ws_size,
                              hipStream_t stream) {
    const float* x   = (const float*)d_in[0];
    const int* ei    = (const int*)d_in[1];
    const int* batch = (const int*)d_in[2];
    const float* w1  = (const float*)d_in[3];
    const float* b1  = (const float*)d_in[4];
    const float* w2  = (const float*)d_in[5];
    const float* b2  = (const float*)d_in[6];
    const float* w3  = (const float*)d_in[7];
    const float* b3  = (const float*)d_in[8];
    const float* g1  = (const float*)d_in[9];
    const float* be1 = (const float*)d_in[10];
    const float* g2  = (const float*)d_in[11];
    const float* be2 = (const float*)d_in[12];
    const float* fcw = (const float*)d_in[13];
    const float* fcb = (const float*)d_in[14];

    const int N = in_sizes[0] / D;
    const int E = in_sizes[1] / 2;
    const int* src = ei;
    const int* dst = ei + E;
    const int nbuck = (N + 255) >> 8;

    char* p = (char*)d_ws;
    auto alloc = [&](size_t bytes) -> void* {
        void* r = (void*)p;
        p += (bytes + 255) & ~(size_t)255;
        return r;
    };
    float* dinv     = (float*)alloc((size_t)N * 4);
    int*   rowPtr   = (int*)alloc((size_t)(N + 1) * 4);
    int*   colIdx   = (int*)alloc((size_t)E * 4);
    u32*   pairs    = (u32*)alloc((size_t)E * 4);
    int*   bucketCnt    = (int*)alloc(NBUCK_MAX * 4);
    int*   bucketBase   = (int*)alloc((NBUCK_MAX + 1) * 4);
    int*   bucketCursor = (int*)alloc(NBUCK_MAX * 4);
    int*   gstart  = (int*)alloc((G_GRAPHS + 1) * 4);
    float* statsacc= (float*)alloc(4 * D * 4);
    float* gsum1 = statsacc, *gsq1 = statsacc + D, *gsum2 = statsacc + 2 * D, *gsq2 = statsacc + 3 * D;
    float* sc1     = (float*)alloc(D * 4);
    float* sh1     = (float*)alloc(D * 4);
    float* sc2     = (float*)alloc(D * 4);
    float* sh2     = (float*)alloc(D * 4);
    float* pooled  = (float*)alloc((size_t)G_GRAPHS * D * 4);
    u16*   wtAll   = (u16*)alloc((size_t)3 * D * D * 2);   // bf16 W^T x3
    u16*   tmp     = (u16*)alloc((size_t)N * D * 2);       // bf16 gemm out
    u16*   hbuf    = (u16*)alloc((size_t)N * D * 2);       // bf16 agg out

    hipMemsetAsync(bucketCnt, 0, NBUCK_MAX * 4, stream);
    hipMemsetAsync(statsacc, 0, 4 * D * 4, stream);

    // ---- graph structure ----
    bucket_hist_kernel<<<512, 256, 0, stream>>>(dst, bucketCnt, E, nbuck);
    scan_buckets_kernel<<<1, 512, 0, stream>>>(bucketCnt, bucketBase, bucketCursor, rowPtr, nbuck, N, E);
    scatter_pairs_kernel<<<(E + EDGE_CHUNK - 1) / EDGE_CHUNK, 256, 0, stream>>>(src, dst, bucketCursor, pairs, E);
    bucket_sort_kernel<<<nbuck, 256, 0, stream>>>(pairs, bucketBase, colIdx, rowPtr, dinv, N);
    graph_bounds_kernel<<<(N + 255) / 256, 256, 0, stream>>>(batch, gstart, N);
    wconv_kernel<<<3, 256, 0, stream>>>((const float4*)w1, (const float4*)w2, (const float4*)w3, wtAll);

    const int GB = (N + 63) / 64;
    const int AB = (N + 3) / 4;

    gemm_mfma_f32in_kernel<<<GB, 256, 0, stream>>>((const float4*)x, wtAll, tmp, N);
    aggregate_kernel<<<AB, 256, 0, stream>>>((const uint4*)tmp, colIdx, rowPtr, dinv, b1, (u32*)hbuf, N);
    gemm_mfma_bf16in_kernel<<<GB, 256, 0, stream>>>((const uint4*)hbuf, wtAll + D * D, nullptr, nullptr, tmp, N);
    aggregate_kernel<<<AB, 256, 0, stream>>>((const uint4*)tmp, colIdx, rowPtr, dinv, b2, (u32*)hbuf, N);
    bn_stats_kernel<<<256, 256, 0, stream>>>((const u32*)hbuf, N, gsum1, gsq1);
    bn_finalize_kernel<<<1, 128, 0, stream>>>(gsum1, gsq1, g1, be1, (float)N, sc1, sh1);
    gemm_mfma_bf16in_kernel<<<GB, 256, 0, stream>>>((const uint4*)hbuf, wtAll + 2 * D * D, sc1, sh1, tmp, N);
    aggregate_kernel<<<AB, 256, 0, stream>>>((const uint4*)tmp, colIdx, rowPtr, dinv, b3, (u32*)hbuf, N);
    bn_stats_kernel<<<256, 256, 0, stream>>>((const u32*)hbuf, N, gsum2, gsq2);
    bn_finalize_kernel<<<1, 128, 0, stream>>>(gsum2, gsq2, g2, be2, (float)N, sc2, sh2);
    pool_kernel<<<G_GRAPHS, 256, 0, stream>>>((const u32*)hbuf, sc2, sh2, gstart, pooled);
    classify_kernel<<<G_GRAPHS, 64, 0, stream>>>(pooled, fcw, fcb, (float*)d_out);
}

// Round 9
// 510.194 us; speedup vs baseline: 2.3190x; 1.0206x over previous
//
#include <hip/hip_runtime.h>
#include <hip/hip_bf16.h>
#include <math.h>

#define D 128
#define G_GRAPHS 512
#define C_CLASSES 10
#define BN_EPS 1e-5f
#define NBUCK_MAX 512     // supports N <= 131072 (bucket = node >> 8)
#define EDGE_CHUNK 4096
#define EPT 16            // EDGE_CHUNK / 256

typedef unsigned short u16;
typedef unsigned int u32;
typedef unsigned short ushort4_t __attribute__((ext_vector_type(4)));
typedef unsigned short ushort8_t __attribute__((ext_vector_type(8)));
typedef __bf16 bf16x8 __attribute__((ext_vector_type(8)));
typedef float floatx4 __attribute__((ext_vector_type(4)));
union B8 { ushort8_t u; bf16x8 b; };

__device__ __forceinline__ float bf_lo(u32 v) { return __uint_as_float(v << 16); }
__device__ __forceinline__ float bf_hi(u32 v) { return __uint_as_float(v & 0xffff0000u); }
__device__ __forceinline__ u16 f2bf(float f) {
    union { float f; u32 u; } x; x.f = f;
    u32 r = x.u + 0x7fff + ((x.u >> 16) & 1);  // RN-even
    return (u16)(r >> 16);
}
__device__ __forceinline__ u32 pack2bf(float a, float b) {
    return (u32)f2bf(a) | ((u32)f2bf(b) << 16);
}

// ============ CSR build: two-level counting sort ============

__global__ __launch_bounds__(256) void bucket_hist_kernel(
    const int* __restrict__ dst, int* __restrict__ bucketCnt, int E, int nbuck)
{
    __shared__ int h[NBUCK_MAX];
    int tid = threadIdx.x;
    for (int i = tid; i < NBUCK_MAX; i += 256) h[i] = 0;
    __syncthreads();
    for (int i = blockIdx.x * 256 + tid; i < E; i += gridDim.x * 256)
        atomicAdd(&h[dst[i] >> 8], 1);
    __syncthreads();
    for (int i = tid; i < nbuck; i += 256)
        if (h[i]) atomicAdd(&bucketCnt[i], h[i]);
}

__global__ void scan_buckets_kernel(
    const int* __restrict__ bucketCnt, int* __restrict__ bucketBase,
    int* __restrict__ bucketCursor, int* __restrict__ rowPtr, int nbuck, int N, int E)
{
    __shared__ int buf[2][512];
    int tid = threadIdx.x;
    int v = (tid < nbuck) ? bucketCnt[tid] : 0;
    buf[0][tid] = v;
    __syncthreads();
    int cur = 0;
    for (int off = 1; off < 512; off <<= 1) {
        buf[1 - cur][tid] = buf[cur][tid] + ((tid >= off) ? buf[cur][tid - off] : 0);
        cur ^= 1;
        __syncthreads();
    }
    if (tid < nbuck) {
        int b = buf[cur][tid] - v;  // exclusive
        bucketBase[tid] = b;
        bucketCursor[tid] = b;
    }
    if (tid == 0) { bucketBase[nbuck] = E; rowPtr[N] = E; }
}

// pairs packed: (src << 8) | (dst & 255)   [src < 2^17, fits 25 bits]
__global__ __launch_bounds__(256) void scatter_pairs_kernel(
    const int* __restrict__ src, const int* __restrict__ dst,
    int* __restrict__ bucketCursor, u32* __restrict__ pairs, int E)
{
    __shared__ int h[NBUCK_MAX];
    __shared__ int base[NBUCK_MAX];
    int tid = threadIdx.x;
    int e0 = blockIdx.x * EDGE_CHUNK;
    for (int i = tid; i < NBUCK_MAX; i += 256) h[i] = 0;
    __syncthreads();
    int s[EPT], d[EPT], r[EPT];
#pragma unroll
    for (int j = 0; j < EPT; ++j) {
        int i = e0 + j * 256 + tid;
        if (i < E) {
            s[j] = src[i];
            d[j] = dst[i];
            r[j] = atomicAdd(&h[d[j] >> 8], 1);
        } else {
            d[j] = -1;
        }
    }
    __syncthreads();
    for (int i = tid; i < NBUCK_MAX; i += 256)
        if (h[i]) base[i] = atomicAdd(&bucketCursor[i], h[i]);
    __syncthreads();
#pragma unroll
    for (int j = 0; j < EPT; ++j) {
        if (d[j] >= 0) {
            int b = d[j] >> 8;
            pairs[base[b] + r[j]] = ((u32)s[j] << 8) | (u32)(d[j] & 255);
        }
    }
}

__global__ __launch_bounds__(256) void bucket_sort_kernel(
    const u32* __restrict__ pairs, const int* __restrict__ bucketBase,
    int* __restrict__ colIdx, int* __restrict__ rowPtr, float* __restrict__ dinv, int N)
{
    __shared__ int h[256];
    __shared__ int cur[256];
    __shared__ int sbuf[2][256];
    int tid = threadIdx.x;
    int b = blockIdx.x;
    int s = bucketBase[b], e = bucketBase[b + 1];
    h[tid] = 0;
    __syncthreads();
    for (int i = s + tid; i < e; i += 256)
        atomicAdd(&h[pairs[i] & 255], 1);
    __syncthreads();
    int cnt = h[tid];
    sbuf[0][tid] = cnt;
    __syncthreads();
    int c = 0;
    for (int off = 1; off < 256; off <<= 1) {
        sbuf[1 - c][tid] = sbuf[c][tid] + ((tid >= off) ? sbuf[c][tid - off] : 0);
        c ^= 1;
        __syncthreads();
    }
    int excl = sbuf[c][tid] - cnt;
    int v = b * 256 + tid;
    if (v < N) {
        rowPtr[v] = s + excl;
        dinv[v] = rsqrtf((float)(cnt + 1));  // +1 self loop
    }
    cur[tid] = s + excl;
    __syncthreads();
    for (int i = s + tid; i < e; i += 256) {
        u32 p = pairs[i];
        int pos = atomicAdd(&cur[p & 255], 1);
        colIdx[pos] = (int)(p >> 8);
    }
}

// ---------------- graph segments: boundary detection on sorted batch ----------------
__global__ __launch_bounds__(256) void graph_bounds_kernel(
    const int* __restrict__ batch, int* __restrict__ gstart, int N)
{
    int i = blockIdx.x * 256 + threadIdx.x;
    if (i >= N) return;
    int b = batch[i];
    int prev = (i == 0) ? -1 : batch[i - 1];
    if (b != prev) {
        for (int g = prev + 1; g <= b; ++g) gstart[g] = i;  // covers empty graphs
    }
    if (i == N - 1) {
        for (int g = b + 1; g <= G_GRAPHS; ++g) gstart[g] = N;
    }
}

// ---------------- W pre-transpose+convert: Wt[n][k] bf16 ----------------
__global__ __launch_bounds__(256) void wconv_kernel(
    const float4* __restrict__ w1, const float4* __restrict__ w2,
    const float4* __restrict__ w3, u16* __restrict__ wtAll)
{
    const float4* W = (blockIdx.x == 0) ? w1 : (blockIdx.x == 1) ? w2 : w3;
    u16* Wt = wtAll + (size_t)blockIdx.x * D * D;
    int tid = threadIdx.x;
#pragma unroll
    for (int i = 0; i < 16; ++i) {
        int idx = tid + i * 256;        // = k*32 + c4
        int k = idx >> 5, c4 = idx & 31;
        float4 v = W[idx];
        Wt[(4 * c4 + 0) * D + k] = f2bf(v.x);
        Wt[(4 * c4 + 1) * D + k] = f2bf(v.y);
        Wt[(4 * c4 + 2) * D + k] = f2bf(v.z);
        Wt[(4 * c4 + 3) * D + k] = f2bf(v.w);
    }
}

// ---------------- MFMA GEMM core (A=W frag, B=X frag; 8B stores) ----------------
#define XS_STRIDE 136
#define GEMM_GRID 768

__device__ __forceinline__ void gemm_core_and_store(
    const u16* Xs, const u16* Ws, u16* __restrict__ Y, int row0, int nrows, int tid)
{
    int wid = tid >> 6, lane = tid & 63;
    int m = lane & 15, quad = lane >> 4;
    int xrow = wid * 16 + m;

    floatx4 acc[8] = {};
#pragma unroll
    for (int ks = 0; ks < 4; ++ks) {
        int kk = ks * 32 + quad * 8;
        B8 a;
        a.u = *(const ushort8_t*)&Xs[xrow * XS_STRIDE + kk];
#pragma unroll
        for (int t = 0; t < 8; ++t) {
            B8 b;
            b.u = *(const ushort8_t*)&Ws[(t * 16 + m) * XS_STRIDE + kk];
            acc[t] = __builtin_amdgcn_mfma_f32_16x16x32_bf16(b.b, a.b, acc[t], 0, 0, 0);
        }
    }
    int grow = row0 + xrow;
    if (grow < nrows) {
#pragma unroll
        for (int t = 0; t < 8; ++t) {
            ushort4_t o;
            o.x = f2bf(acc[t][0]); o.y = f2bf(acc[t][1]);
            o.z = f2bf(acc[t][2]); o.w = f2bf(acc[t][3]);
            *(ushort4_t*)&Y[(size_t)grow * D + t * 16 + quad * 4] = o;
        }
    }
}

__device__ __forceinline__ void stage_w(const u16* __restrict__ Wt, u16* Ws, int tid) {
    const ushort8_t* Wv = (const ushort8_t*)Wt;
#pragma unroll
    for (int i = 0; i < 8; ++i) {
        int idx = tid + i * 256;        // = n*16 + c8
        int n = idx >> 4, c8 = idx & 15;
        *(ushort8_t*)&Ws[n * XS_STRIDE + c8 * 8] = Wv[idx];
    }
}

// layer 1: X fp32, persistent tiles
__global__ __launch_bounds__(256) void gemm_mfma_f32in_kernel(
    const float4* __restrict__ X, const u16* __restrict__ Wt,
    u16* __restrict__ Y, int nrows, int ntiles)
{
    __shared__ __align__(16) u16 Xs[64 * XS_STRIDE];
    __shared__ __align__(16) u16 Ws[128 * XS_STRIDE];
    int tid = threadIdx.x;
    stage_w(Wt, Ws, tid);
    for (int t = blockIdx.x; t < ntiles; t += gridDim.x) {
        int row0 = t * 64;
        __syncthreads();   // Ws ready / prev tile's reads done
#pragma unroll
        for (int i = 0; i < 8; ++i) {
            int idx = tid + i * 256;        // = r*32 + c4
            int r = idx >> 5, c4 = idx & 31;
            int gr = row0 + r;
            float4 v = make_float4(0.f, 0.f, 0.f, 0.f);
            if (gr < nrows) v = X[(size_t)gr * 32 + c4];
            ushort4_t o;
            o.x = f2bf(v.x); o.y = f2bf(v.y); o.z = f2bf(v.z); o.w = f2bf(v.w);
            *(ushort4_t*)&Xs[r * XS_STRIDE + c4 * 4] = o;
        }
        __syncthreads();
        gemm_core_and_store(Xs, Ws, Y, row0, nrows, tid);
    }
}

// layers 2/3: X bf16, optional fused bn(from raw stats)+relu on input, persistent
__global__ __launch_bounds__(256) void gemm_mfma_bf16in_kernel(
    const uint4* __restrict__ X, const u16* __restrict__ Wt,
    const float* __restrict__ gsum, const float* __restrict__ gsq,
    const float* __restrict__ gamma, const float* __restrict__ beta, float invN,
    u16* __restrict__ Y, int nrows, int ntiles)
{
    __shared__ __align__(16) u16 Xs[64 * XS_STRIDE];
    __shared__ __align__(16) u16 Ws[128 * XS_STRIDE];
    __shared__ float scs[D], shs[D];
    int tid = threadIdx.x;
    bool fuse = (gsum != nullptr);
    stage_w(Wt, Ws, tid);
    if (fuse && tid < D) {
        float mu = gsum[tid] * invN;
        float var = gsq[tid] * invN - mu * mu;
        float sc = gamma[tid] * rsqrtf(var + BN_EPS);
        scs[tid] = sc;
        shs[tid] = beta[tid] - mu * sc;
    }
    for (int t = blockIdx.x; t < ntiles; t += gridDim.x) {
        int row0 = t * 64;
        __syncthreads();   // Ws/scs ready / prev tile's reads done
#pragma unroll
        for (int i = 0; i < 4; ++i) {
            int idx = tid + i * 256;        // = r*16 + c8
            int r = idx >> 4, c8 = idx & 15;
            int gr = row0 + r;
            uint4 v = make_uint4(0, 0, 0, 0);
            if (gr < nrows) v = X[(size_t)gr * 16 + c8];
            if (fuse) {
                int k = c8 * 8;
                v.x = pack2bf(fmaxf(bf_lo(v.x) * scs[k]     + shs[k],     0.f),
                              fmaxf(bf_hi(v.x) * scs[k + 1] + shs[k + 1], 0.f));
                v.y = pack2bf(fmaxf(bf_lo(v.y) * scs[k + 2] + shs[k + 2], 0.f),
                              fmaxf(bf_hi(v.y) * scs[k + 3] + shs[k + 3], 0.f));
                v.z = pack2bf(fmaxf(bf_lo(v.z) * scs[k + 4] + shs[k + 4], 0.f),
                              fmaxf(bf_hi(v.z) * scs[k + 5] + shs[k + 5], 0.f));
                v.w = pack2bf(fmaxf(bf_lo(v.w) * scs[k + 6] + shs[k + 6], 0.f),
                              fmaxf(bf_hi(v.w) * scs[k + 7] + shs[k + 7], 0.f));
            }
            *(uint4*)&Xs[r * XS_STRIDE + c8 * 8] = v;
        }
        __syncthreads();
        gemm_core_and_store(Xs, Ws, Y, row0, nrows, tid);
    }
}

// ---------------- aggregation v4: 4-deep gathers, byte-offset shfl ----------------
#define ACC8(tw, duu)                                              \
    acc[0] += (duu) * bf_lo((tw).x); acc[1] += (duu) * bf_hi((tw).x); \
    acc[2] += (duu) * bf_lo((tw).y); acc[3] += (duu) * bf_hi((tw).y); \
    acc[4] += (duu) * bf_lo((tw).z); acc[5] += (duu) * bf_hi((tw).z); \
    acc[6] += (duu) * bf_lo((tw).w); acc[7] += (duu) * bf_hi((tw).w);

__global__ __launch_bounds__(256) void aggregate_kernel(
    const uint4* __restrict__ T, const int* __restrict__ colIdx,
    const int* __restrict__ rowPtr, const float* __restrict__ dinv,
    const float* __restrict__ bias, u32* __restrict__ outH, int n)
{
    int wid = threadIdx.x >> 6;
    int lane = threadIdx.x & 63;
    int row = blockIdx.x * 4 + wid;
    if (row >= n) return;
    int fg = lane & 15;
    int eg = lane >> 4;
    const char* baseT = (const char*)T + fg * 16;

    float dr = dinv[row];
    float acc[8] = {};

    if (eg == 0) {
        uint4 sv = T[(size_t)row * 16 + fg];
        acc[0] = dr * bf_lo(sv.x); acc[1] = dr * bf_hi(sv.x);
        acc[2] = dr * bf_lo(sv.y); acc[3] = dr * bf_hi(sv.y);
        acc[4] = dr * bf_lo(sv.z); acc[5] = dr * bf_hi(sv.z);
        acc[6] = dr * bf_lo(sv.w); acc[7] = dr * bf_hi(sv.w);
    }

    int s = rowPtr[row], e = rowPtr[row + 1];
    for (int j0 = s; j0 < e; j0 += 64) {
        int m = e - j0;
        if (m > 64) m = 64;
        u32 voff = (u32)row << 8;   // inactive lanes: row's own (hot) line, weight 0
        float du = 0.f;
        if (lane < m) {
            int u = colIdx[j0 + lane];
            voff = (u32)u << 8;     // byte offset: u * 256
            du = dinv[u];
        }
        int nc = (m + 15) >> 4;  // 16-edge sub-chunks; 4 edges per group
        for (int c = 0; c < nc; ++c) {
            int b0 = c * 16 + eg;
            u32 o0 = (u32)__shfl((int)voff, b0);      u32 o1 = (u32)__shfl((int)voff, b0 + 4);
            u32 o2 = (u32)__shfl((int)voff, b0 + 8);  u32 o3 = (u32)__shfl((int)voff, b0 + 12);
            float d0 = __shfl(du, b0);      float d1 = __shfl(du, b0 + 4);
            float d2 = __shfl(du, b0 + 8);  float d3 = __shfl(du, b0 + 12);
            uint4 t0 = *(const uint4*)(baseT + o0);
            uint4 t1 = *(const uint4*)(baseT + o1);
            uint4 t2 = *(const uint4*)(baseT + o2);
            uint4 t3 = *(const uint4*)(baseT + o3);
            ACC8(t0, d0); ACC8(t1, d1); ACC8(t2, d2); ACC8(t3, d3);
        }
    }

#pragma unroll
    for (int off = 16; off < 64; off <<= 1) {
#pragma unroll
        for (int i = 0; i < 8; ++i) acc[i] += __shfl_xor(acc[i], off);
    }

    const float2* bp = (const float2*)bias;
    int pidx = fg * 4 + eg;
    float2 b = bp[pidx];
    float ox = fmaxf(dr * acc[eg * 2] + b.x, 0.f);
    float oy = fmaxf(dr * acc[eg * 2 + 1] + b.y, 0.f);
    outH[(size_t)row * 64 + pidx] = pack2bf(ox, oy);
}

// ---------------- batchnorm stats (bf16 input) ----------------
__global__ __launch_bounds__(256) void bn_stats_kernel(
    const u32* __restrict__ H, int n, float* __restrict__ gsum, float* __restrict__ gsq)
{
    int tid = threadIdx.x;
    int c = tid & 63, rr = tid >> 6;
    float sA = 0.f, sA2 = 0.f, sB = 0.f, sB2 = 0.f;
    for (int row = blockIdx.x * 4 + rr; row < n; row += gridDim.x * 4) {
        u32 v = H[(size_t)row * 64 + c];
        float a = bf_lo(v), b = bf_hi(v);
        sA += a; sA2 += a * a; sB += b; sB2 += b * b;
    }
    __shared__ float shA[256], shA2[256], shB[256], shB2[256];
    shA[tid] = sA; shA2[tid] = sA2; shB[tid] = sB; shB2[tid] = sB2;
    __syncthreads();
    if (tid < 64) {
        float tA = shA[tid] + shA[tid + 64] + shA[tid + 128] + shA[tid + 192];
        float tA2 = shA2[tid] + shA2[tid + 64] + shA2[tid + 128] + shA2[tid + 192];
        float tB = shB[tid] + shB[tid + 64] + shB[tid + 128] + shB[tid + 192];
        float tB2 = shB2[tid] + shB2[tid + 64] + shB2[tid + 128] + shB2[tid + 192];
        atomicAdd(&gsum[2 * c], tA);
        atomicAdd(&gsq[2 * c], tA2);
        atomicAdd(&gsum[2 * c + 1], tB);
        atomicAdd(&gsq[2 * c + 1], tB2);
    }
}

// ---------------- pool (bn2 from raw stats + relu) + classify + log_softmax ----------------
__global__ __launch_bounds__(256) void pool_classify_kernel(
    const u32* __restrict__ H, const float* __restrict__ gsum, const float* __restrict__ gsq,
    const float* __restrict__ gamma, const float* __restrict__ beta, float invN,
    const int* __restrict__ gstart, const float* __restrict__ fcw,
    const float* __restrict__ fcb, float* __restrict__ out)
{
    int g = blockIdx.x;
    int tid = threadIdx.x;
    int c = tid & 63, q = tid >> 6;
    // bn2 scale/shift for features 2c, 2c+1 (redundant across q — cheap)
    float muA = gsum[2 * c] * invN, muB = gsum[2 * c + 1] * invN;
    float vA = gsq[2 * c] * invN - muA * muA, vB = gsq[2 * c + 1] * invN - muB * muB;
    float scA = gamma[2 * c] * rsqrtf(vA + BN_EPS), scB = gamma[2 * c + 1] * rsqrtf(vB + BN_EPS);
    float shA = beta[2 * c] - muA * scA, shB = beta[2 * c + 1] - muB * scB;

    int s = gstart[g], cnt = gstart[g + 1] - s;
    float aA = 0.f, aB = 0.f;
    for (int i = q; i < cnt; i += 4) {
        u32 v = H[(size_t)(s + i) * 64 + c];
        aA += fmaxf(bf_lo(v) * scA + shA, 0.f);
        aB += fmaxf(bf_hi(v) * scB + shB, 0.f);
    }
    __shared__ float sA[256], sB[256];
    __shared__ float prow[D];
    __shared__ float lg[C_CLASSES];
    sA[tid] = aA; sB[tid] = aB;
    __syncthreads();
    if (tid < 64) {
        float tA = sA[tid] + sA[tid + 64] + sA[tid + 128] + sA[tid + 192];
        float tB = sB[tid] + sB[tid + 64] + sB[tid + 128] + sB[tid + 192];
        float inv = 1.f / (float)(cnt > 1 ? cnt : 1);
        prow[2 * tid] = tA * inv;
        prow[2 * tid + 1] = tB * inv;
    }
    __syncthreads();
    if (tid < C_CLASSES) {
        float sum = fcb[tid];
        for (int d = 0; d < D; ++d) sum += prow[d] * fcw[d * C_CLASSES + tid];
        lg[tid] = sum;
    }
    __syncthreads();
    if (tid == 0) {
        float mx = -1e30f;
        for (int k = 0; k < C_CLASSES; ++k) mx = fmaxf(mx, lg[k]);
        float se = 0.f;
        for (int k = 0; k < C_CLASSES; ++k) se += expf(lg[k] - mx);
        float lse = mx + logf(se);
        for (int k = 0; k < C_CLASSES; ++k) out[(size_t)g * C_CLASSES + k] = lg[k] - lse;
    }
}

extern "C" void kernel_launch(void* const* d_in, const int* in_sizes, int n_in,
                              void* d_out, int out_size, void* d_ws, size_t ws_size,
                              hipStream_t stream) {
    const float* x   = (const float*)d_in[0];
    const int* ei    = (const int*)d_in[1];
    const int* batch = (const int*)d_in[2];
    const float* w1  = (const float*)d_in[3];
    const float* b1  = (const float*)d_in[4];
    const float* w2  = (const float*)d_in[5];
    const float* b2  = (const float*)d_in[6];
    const float* w3  = (const float*)d_in[7];
    const float* b3  = (const float*)d_in[8];
    const float* g1  = (const float*)d_in[9];
    const float* be1 = (const float*)d_in[10];
    const float* g2  = (const float*)d_in[11];
    const float* be2 = (const float*)d_in[12];
    const float* fcw = (const float*)d_in[13];
    const float* fcb = (const float*)d_in[14];

    const int N = in_sizes[0] / D;
    const int E = in_sizes[1] / 2;
    const int* src = ei;
    const int* dst = ei + E;
    const int nbuck = (N + 255) >> 8;
    const float invN = 1.f / (float)N;

    char* p = (char*)d_ws;
    auto alloc = [&](size_t bytes) -> void* {
        void* r = (void*)p;
        p += (bytes + 255) & ~(size_t)255;
        return r;
    };
    // bucketCnt + statsacc adjacent -> one memset
    int*   bucketCnt    = (int*)alloc(NBUCK_MAX * 4);
    float* statsacc     = (float*)alloc(4 * D * 4);
    float* gsum1 = statsacc, *gsq1 = statsacc + D, *gsum2 = statsacc + 2 * D, *gsq2 = statsacc + 3 * D;
    float* dinv     = (float*)alloc((size_t)N * 4);
    int*   rowPtr   = (int*)alloc((size_t)(N + 1) * 4);
    int*   colIdx   = (int*)alloc((size_t)E * 4);
    u32*   pairs    = (u32*)alloc((size_t)E * 4);
    int*   bucketBase   = (int*)alloc((NBUCK_MAX + 1) * 4);
    int*   bucketCursor = (int*)alloc(NBUCK_MAX * 4);
    int*   gstart  = (int*)alloc((G_GRAPHS + 1) * 4);
    u16*   wtAll   = (u16*)alloc((size_t)3 * D * D * 2);   // bf16 W^T x3
    u16*   tmp     = (u16*)alloc((size_t)N * D * 2);       // bf16 gemm out
    u16*   hbuf    = (u16*)alloc((size_t)N * D * 2);       // bf16 agg out

    hipMemsetAsync(bucketCnt, 0, NBUCK_MAX * 4 + 4 * D * 4, stream);

    // ---- graph structure ----
    bucket_hist_kernel<<<512, 256, 0, stream>>>(dst, bucketCnt, E, nbuck);
    scan_buckets_kernel<<<1, 512, 0, stream>>>(bucketCnt, bucketBase, bucketCursor, rowPtr, nbuck, N, E);
    scatter_pairs_kernel<<<(E + EDGE_CHUNK - 1) / EDGE_CHUNK, 256, 0, stream>>>(src, dst, bucketCursor, pairs, E);
    bucket_sort_kernel<<<nbuck, 256, 0, stream>>>(pairs, bucketBase, colIdx, rowPtr, dinv, N);
    graph_bounds_kernel<<<(N + 255) / 256, 256, 0, stream>>>(batch, gstart, N);
    wconv_kernel<<<3, 256, 0, stream>>>((const float4*)w1, (const float4*)w2, (const float4*)w3, wtAll);

    const int NT = (N + 63) / 64;            // gemm tiles
    const int GB = NT < GEMM_GRID ? NT : GEMM_GRID;
    const int AB = (N + 3) / 4;

    gemm_mfma_f32in_kernel<<<GB, 256, 0, stream>>>((const float4*)x, wtAll, tmp, N, NT);
    aggregate_kernel<<<AB, 256, 0, stream>>>((const uint4*)tmp, colIdx, rowPtr, dinv, b1, (u32*)hbuf, N);
    gemm_mfma_bf16in_kernel<<<GB, 256, 0, stream>>>((const uint4*)hbuf, wtAll + D * D,
        nullptr, nullptr, nullptr, nullptr, 0.f, tmp, N, NT);
    aggregate_kernel<<<AB, 256, 0, stream>>>((const uint4*)tmp, colIdx, rowPtr, dinv, b2, (u32*)hbuf, N);
    bn_stats_kernel<<<256, 256, 0, stream>>>((const u32*)hbuf, N, gsum1, gsq1);
    gemm_mfma_bf16in_kernel<<<GB, 256, 0, stream>>>((const uint4*)hbuf, wtAll + 2 * D * D,
        gsum1, gsq1, g1, be1, invN, tmp, N, NT);
    aggregate_kernel<<<AB, 256, 0, stream>>>((const uint4*)tmp, colIdx, rowPtr, dinv, b3, (u32*)hbuf, N);
    bn_stats_kernel<<<256, 256, 0, stream>>>((const u32*)hbuf, N, gsum2, gsq2);
    pool_classify_kernel<<<G_GRAPHS, 256, 0, stream>>>((const u32*)hbuf, gsum2, gsq2, g2, be2, invN,
        gstart, fcw, fcb, (float*)d_out);
}